// Round 1
// baseline (6343.335 us; speedup 1.0000x reference)
//
#include <hip/hip_runtime.h>

#define N_NODES 50000
#define N_EDGES 800000
#define IN_DIM 768
#define HIDDEN 256
#define N_CLASSES 10
#define N_GRAPHS 128

// ---------------- degree / norm ----------------
__global__ void init_deg(float* deg) {
    int i = blockIdx.x * blockDim.x + threadIdx.x;
    if (i < N_NODES) deg[i] = 1.0f;  // self-loop
}

__global__ void deg_count(const int* __restrict__ dst, float* deg) {
    int e = blockIdx.x * blockDim.x + threadIdx.x;
    if (e < N_EDGES) atomicAdd(&deg[dst[e]], 1.0f);
}

__global__ void make_dinv(float* deg) {
    int i = blockIdx.x * blockDim.x + threadIdx.x;
    if (i < N_NODES) deg[i] = rsqrtf(deg[i]);  // deg >= 1 always
}

// ---------------- GEMM: C[M,256] = A[M,K] * B[K,256] ----------------
// 64x64 tile, 256 threads, 4x4 microtile, BK=16.
__global__ __launch_bounds__(256) void gemm_n256(const float* __restrict__ A,
                                                 const float* __restrict__ B,
                                                 float* __restrict__ C,
                                                 int M, int K) {
    __shared__ float As[64][17];
    __shared__ float Bs[16][68];

    const int tx = threadIdx.x & 15;   // 0..15 col group
    const int ty = threadIdx.x >> 4;   // 0..15 row group
    const int bm = blockIdx.x * 64;
    const int bn = blockIdx.y * 64;

    const int la_row = threadIdx.x >> 2;        // 0..63
    const int la_c4  = (threadIdx.x & 3) * 4;   // 0,4,8,12
    const int lb_row = threadIdx.x >> 4;        // 0..15
    const int lb_c4  = (threadIdx.x & 15) * 4;  // 0..60

    float acc[4][4] = {};

    for (int k0 = 0; k0 < K; k0 += 16) {
        // load A tile 64x16
        int ar = bm + la_row;
        float4 av = make_float4(0.f, 0.f, 0.f, 0.f);
        if (ar < M) av = *(const float4*)&A[(size_t)ar * K + k0 + la_c4];
        As[la_row][la_c4 + 0] = av.x;
        As[la_row][la_c4 + 1] = av.y;
        As[la_row][la_c4 + 2] = av.z;
        As[la_row][la_c4 + 3] = av.w;
        // load B tile 16x64
        float4 bv = *(const float4*)&B[(size_t)(k0 + lb_row) * 256 + bn + lb_c4];
        *(float4*)&Bs[lb_row][lb_c4] = bv;
        __syncthreads();

#pragma unroll
        for (int kk = 0; kk < 16; ++kk) {
            float a0 = As[ty * 4 + 0][kk];
            float a1 = As[ty * 4 + 1][kk];
            float a2 = As[ty * 4 + 2][kk];
            float a3 = As[ty * 4 + 3][kk];
            float4 b = *(float4*)&Bs[kk][tx * 4];
            acc[0][0] += a0 * b.x; acc[0][1] += a0 * b.y; acc[0][2] += a0 * b.z; acc[0][3] += a0 * b.w;
            acc[1][0] += a1 * b.x; acc[1][1] += a1 * b.y; acc[1][2] += a1 * b.z; acc[1][3] += a1 * b.w;
            acc[2][0] += a2 * b.x; acc[2][1] += a2 * b.y; acc[2][2] += a2 * b.z; acc[2][3] += a2 * b.w;
            acc[3][0] += a3 * b.x; acc[3][1] += a3 * b.y; acc[3][2] += a3 * b.z; acc[3][3] += a3 * b.w;
        }
        __syncthreads();
    }

#pragma unroll
    for (int i = 0; i < 4; ++i) {
        int row = bm + ty * 4 + i;
        if (row < M) {
            float4 v = make_float4(acc[i][0], acc[i][1], acc[i][2], acc[i][3]);
            *(float4*)&C[(size_t)row * 256 + bn + tx * 4] = v;
        }
    }
}

// ---------------- self-loop init: x = h * dinv^2 ----------------
__global__ void self_init(const float* __restrict__ h, const float* __restrict__ dinv,
                          float* __restrict__ x) {
    int gid = blockIdx.x * blockDim.x + threadIdx.x;  // N_NODES*64 threads
    if (gid >= N_NODES * 64) return;
    int node = gid >> 6;
    float di = dinv[node];
    float w = di * di;
    float4 v = *(const float4*)&h[(size_t)gid * 4];
    v.x *= w; v.y *= w; v.z *= w; v.w *= w;
    *(float4*)&x[(size_t)gid * 4] = v;
}

// ---------------- edge aggregation: x[dst] += h[src]*dinv[src]*dinv[dst] ----
__global__ __launch_bounds__(256) void edge_agg(const int* __restrict__ src,
                                                const int* __restrict__ dst,
                                                const float* __restrict__ h,
                                                const float* __restrict__ dinv,
                                                float* __restrict__ out) {
    int gid = blockIdx.x * blockDim.x + threadIdx.x;
    int e = gid >> 6;
    if (e >= N_EDGES) return;
    int lane = gid & 63;
    int s = src[e], d = dst[e];
    float nrm = dinv[s] * dinv[d];
    float4 v = *(const float4*)&h[(size_t)s * 256 + lane * 4];
    float* o = &out[(size_t)d * 256 + lane * 4];
    atomicAdd(o + 0, v.x * nrm);
    atomicAdd(o + 1, v.y * nrm);
    atomicAdd(o + 2, v.z * nrm);
    atomicAdd(o + 3, v.w * nrm);
}

// ---------------- bias (+optional relu) ----------------
template <bool RELU>
__global__ void add_bias(float* __restrict__ x, const float* __restrict__ b) {
    int gid = blockIdx.x * blockDim.x + threadIdx.x;  // N_NODES*64
    if (gid >= N_NODES * 64) return;
    int c4 = (gid & 63) * 4;
    float4 v = *(float4*)&x[(size_t)gid * 4];
    float4 bb = *(const float4*)&b[c4];
    v.x += bb.x; v.y += bb.y; v.z += bb.z; v.w += bb.w;
    if (RELU) {
        v.x = fmaxf(v.x, 0.f); v.y = fmaxf(v.y, 0.f);
        v.z = fmaxf(v.z, 0.f); v.w = fmaxf(v.w, 0.f);
    }
    *(float4*)&x[(size_t)gid * 4] = v;
}

// ---------------- pooling ----------------
__global__ void zero_f32(float* p, int n) {
    int i = blockIdx.x * blockDim.x + threadIdx.x;
    if (i < n) p[i] = 0.f;
}

__global__ __launch_bounds__(256) void pool_kernel(const float* __restrict__ x,
                                                   const int* __restrict__ batch,
                                                   float* __restrict__ gsum,
                                                   float* __restrict__ gcnt) {
    int gid = blockIdx.x * blockDim.x + threadIdx.x;  // N_NODES*64
    if (gid >= N_NODES * 64) return;
    int node = gid >> 6;
    int lane = gid & 63;
    int g = batch[node];
    float4 v = *(const float4*)&x[(size_t)gid * 4];
    float* o = &gsum[(size_t)g * 256 + lane * 4];
    atomicAdd(o + 0, v.x);
    atomicAdd(o + 1, v.y);
    atomicAdd(o + 2, v.z);
    atomicAdd(o + 3, v.w);
    if (lane == 0) atomicAdd(&gcnt[g], 1.0f);
}

// ---------------- FC head ----------------
__global__ __launch_bounds__(64) void fc_head(const float* __restrict__ gsum,
                                              const float* __restrict__ gcnt,
                                              const float* __restrict__ Wfc,
                                              const float* __restrict__ bfc,
                                              float* __restrict__ out) {
    int g = blockIdx.x;
    __shared__ float pooled[256];
    float inv = 1.0f / fmaxf(gcnt[g], 1.0f);
    for (int c = threadIdx.x; c < 256; c += 64) pooled[c] = gsum[(size_t)g * 256 + c] * inv;
    __syncthreads();
    if (threadIdx.x < N_CLASSES) {
        float s = bfc[threadIdx.x];
        for (int c = 0; c < 256; ++c) s += pooled[c] * Wfc[c * N_CLASSES + threadIdx.x];
        out[g * N_CLASSES + threadIdx.x] = s;
    }
}

extern "C" void kernel_launch(void* const* d_in, const int* in_sizes, int n_in,
                              void* d_out, int out_size, void* d_ws, size_t ws_size,
                              hipStream_t stream) {
    const float* emb  = (const float*)d_in[0];
    const int*   eidx = (const int*)d_in[1];
    const int*   batch= (const int*)d_in[2];
    const float* W1   = (const float*)d_in[3];
    const float* b1   = (const float*)d_in[4];
    const float* W2   = (const float*)d_in[5];
    const float* b2   = (const float*)d_in[6];
    const float* Wfc  = (const float*)d_in[7];
    const float* bfc  = (const float*)d_in[8];
    float* out = (float*)d_out;

    const int* src = eidx;
    const int* dst = eidx + N_EDGES;

    char* ws = (char*)d_ws;
    float* deg  = (float*)ws;                                   // 200000 B
    float* bufA = (float*)(ws + 200192);                        // 51.2 MB  (h)
    float* bufB = (float*)(ws + 200192 + 51200000);             // 51.2 MB  (x)
    float* gsum = (float*)(ws + 200192 + 2 * 51200000);         // 131072 B
    float* gcnt = gsum + N_GRAPHS * HIDDEN;                     // 512 B

    const int ELEMS64 = N_NODES * 64;                 // float4-granule count
    const int EB = (ELEMS64 + 255) / 256;             // 12500 blocks
    dim3 gemm_grid((N_NODES + 63) / 64, 4);

    // degrees -> dinv (in place in `deg`)
    init_deg<<<(N_NODES + 255) / 256, 256, 0, stream>>>(deg);
    deg_count<<<(N_EDGES + 255) / 256, 256, 0, stream>>>(dst, deg);
    make_dinv<<<(N_NODES + 255) / 256, 256, 0, stream>>>(deg);

    // conv1
    gemm_n256<<<gemm_grid, 256, 0, stream>>>(emb, W1, bufA, N_NODES, IN_DIM);
    self_init<<<EB, 256, 0, stream>>>(bufA, deg, bufB);
    edge_agg<<<(N_EDGES * 64) / 256, 256, 0, stream>>>(src, dst, bufA, deg, bufB);
    add_bias<true><<<EB, 256, 0, stream>>>(bufB, b1);

    // conv2
    gemm_n256<<<gemm_grid, 256, 0, stream>>>(bufB, W2, bufA, N_NODES, HIDDEN);
    self_init<<<EB, 256, 0, stream>>>(bufA, deg, bufB);
    edge_agg<<<(N_EDGES * 64) / 256, 256, 0, stream>>>(src, dst, bufA, deg, bufB);
    add_bias<false><<<EB, 256, 0, stream>>>(bufB, b2);

    // pool + head
    zero_f32<<<(N_GRAPHS * HIDDEN + N_GRAPHS + 255) / 256, 256, 0, stream>>>(gsum, N_GRAPHS * HIDDEN + N_GRAPHS);
    pool_kernel<<<EB, 256, 0, stream>>>(bufB, batch, gsum, gcnt);
    fc_head<<<N_GRAPHS, 64, 0, stream>>>(gsum, gcnt, Wfc, bfc, out);
}

// Round 6
// 977.813 us; speedup vs baseline: 6.4873x; 6.4873x over previous
//
#include <hip/hip_runtime.h>

#define N_NODES 50000
#define N_EDGES 800000
#define IN_DIM 768
#define HIDDEN 256
#define N_CLASSES 10
#define N_GRAPHS 128

// ---------------- CSR build ----------------
__global__ void zero_int(int* p, int n) {
    int i = blockIdx.x * blockDim.x + threadIdx.x;
    if (i < n) p[i] = 0;
}

__global__ void hist_dst(const int* __restrict__ dst, int* __restrict__ cnt) {
    int e = blockIdx.x * blockDim.x + threadIdx.x;
    if (e < N_EDGES) atomicAdd(&cnt[dst[e]], 1);
}

__global__ void make_dinv(const int* __restrict__ cnt, float* __restrict__ dinv) {
    int i = blockIdx.x * blockDim.x + threadIdx.x;
    if (i < N_NODES) dinv[i] = rsqrtf(1.0f + (float)cnt[i]);  // +1 self-loop
}

// single-block exclusive scan over 50K counts -> rowstart, cursor
__global__ __launch_bounds__(1024) void scan_kernel(const int* __restrict__ cnt,
                                                    int* __restrict__ rowstart,
                                                    int* __restrict__ cursor) {
    __shared__ int smem[1024];
    __shared__ int carry;
    if (threadIdx.x == 0) carry = 0;
    __syncthreads();
    for (int base = 0; base < N_NODES; base += 1024) {
        int i = base + threadIdx.x;
        int v = (i < N_NODES) ? cnt[i] : 0;
        smem[threadIdx.x] = v;
        __syncthreads();
        for (int off = 1; off < 1024; off <<= 1) {
            int t = (threadIdx.x >= off) ? smem[threadIdx.x - off] : 0;
            __syncthreads();
            smem[threadIdx.x] += t;
            __syncthreads();
        }
        int excl = carry + smem[threadIdx.x] - v;
        if (i < N_NODES) { rowstart[i] = excl; cursor[i] = excl; }
        __syncthreads();
        if (threadIdx.x == 1023) carry += smem[1023];
        __syncthreads();
    }
    if (threadIdx.x == 0) rowstart[N_NODES] = carry;
}

__global__ void scatter_edges(const int* __restrict__ src, const int* __restrict__ dst,
                              int* __restrict__ cursor, int* __restrict__ col) {
    int e = blockIdx.x * blockDim.x + threadIdx.x;
    if (e >= N_EDGES) return;
    int d = dst[e];
    int pos = atomicAdd(&cursor[d], 1);
    col[pos] = src[e];
}

// ---------------- GEMM: C[M,256] = A[M,K] * B[K,256] ----------------
__global__ __launch_bounds__(256) void gemm_n256(const float* __restrict__ A,
                                                 const float* __restrict__ B,
                                                 float* __restrict__ C,
                                                 int M, int K) {
    __shared__ float As[64][17];
    __shared__ float Bs[16][68];

    const int tx = threadIdx.x & 15;
    const int ty = threadIdx.x >> 4;
    const int bm = blockIdx.x * 64;
    const int bn = blockIdx.y * 64;

    const int la_row = threadIdx.x >> 2;
    const int la_c4  = (threadIdx.x & 3) * 4;
    const int lb_row = threadIdx.x >> 4;
    const int lb_c4  = (threadIdx.x & 15) * 4;

    float acc[4][4] = {};

    for (int k0 = 0; k0 < K; k0 += 16) {
        int ar = bm + la_row;
        float4 av = make_float4(0.f, 0.f, 0.f, 0.f);
        if (ar < M) av = *(const float4*)&A[(size_t)ar * K + k0 + la_c4];
        As[la_row][la_c4 + 0] = av.x;
        As[la_row][la_c4 + 1] = av.y;
        As[la_row][la_c4 + 2] = av.z;
        As[la_row][la_c4 + 3] = av.w;
        float4 bv = *(const float4*)&B[(size_t)(k0 + lb_row) * 256 + bn + lb_c4];
        *(float4*)&Bs[lb_row][lb_c4] = bv;
        __syncthreads();

#pragma unroll
        for (int kk = 0; kk < 16; ++kk) {
            float a0 = As[ty * 4 + 0][kk];
            float a1 = As[ty * 4 + 1][kk];
            float a2 = As[ty * 4 + 2][kk];
            float a3 = As[ty * 4 + 3][kk];
            float4 b = *(float4*)&Bs[kk][tx * 4];
            acc[0][0] += a0 * b.x; acc[0][1] += a0 * b.y; acc[0][2] += a0 * b.z; acc[0][3] += a0 * b.w;
            acc[1][0] += a1 * b.x; acc[1][1] += a1 * b.y; acc[1][2] += a1 * b.z; acc[1][3] += a1 * b.w;
            acc[2][0] += a2 * b.x; acc[2][1] += a2 * b.y; acc[2][2] += a2 * b.z; acc[2][3] += a2 * b.w;
            acc[3][0] += a3 * b.x; acc[3][1] += a3 * b.y; acc[3][2] += a3 * b.z; acc[3][3] += a3 * b.w;
        }
        __syncthreads();
    }

#pragma unroll
    for (int i = 0; i < 4; ++i) {
        int row = bm + ty * 4 + i;
        if (row < M) {
            float4 v = make_float4(acc[i][0], acc[i][1], acc[i][2], acc[i][3]);
            *(float4*)&C[(size_t)row * 256 + bn + tx * 4] = v;
        }
    }
}

// ---------------- CSR aggregation (gather), fused self-loop + bias (+relu) ---
// one wave per destination node; lane owns 4 contiguous cols (float4)
template <bool RELU>
__global__ __launch_bounds__(256) void agg_csr(const float* __restrict__ h,
                                               const float* __restrict__ dinv,
                                               const int* __restrict__ rowstart,
                                               const int* __restrict__ col,
                                               const float* __restrict__ bias,
                                               float* __restrict__ out) {
    int node = (blockIdx.x * 256 + threadIdx.x) >> 6;
    if (node >= N_NODES) return;
    int lane = threadIdx.x & 63;

    float dd = dinv[node];
    const float4* hrow = (const float4*)&h[(size_t)node * 256];
    float4 acc = hrow[lane];
    float w = dd * dd;
    acc.x *= w; acc.y *= w; acc.z *= w; acc.w *= w;

    int j = rowstart[node], jend = rowstart[node + 1];
    for (; j + 1 < jend; j += 2) {
        int sa = col[j], sb = col[j + 1];
        float na = dinv[sa] * dd, nb = dinv[sb] * dd;
        float4 va = *(const float4*)&h[(size_t)sa * 256 + (lane << 2)];
        float4 vb = *(const float4*)&h[(size_t)sb * 256 + (lane << 2)];
        acc.x += va.x * na + vb.x * nb;
        acc.y += va.y * na + vb.y * nb;
        acc.z += va.z * na + vb.z * nb;
        acc.w += va.w * na + vb.w * nb;
    }
    if (j < jend) {
        int sa = col[j];
        float na = dinv[sa] * dd;
        float4 va = *(const float4*)&h[(size_t)sa * 256 + (lane << 2)];
        acc.x += va.x * na; acc.y += va.y * na; acc.z += va.z * na; acc.w += va.w * na;
    }

    float4 bb = *(const float4*)&bias[lane << 2];
    acc.x += bb.x; acc.y += bb.y; acc.z += bb.z; acc.w += bb.w;
    if (RELU) {
        acc.x = fmaxf(acc.x, 0.f); acc.y = fmaxf(acc.y, 0.f);
        acc.z = fmaxf(acc.z, 0.f); acc.w = fmaxf(acc.w, 0.f);
    }
    *(float4*)&out[(size_t)node * 256 + (lane << 2)] = acc;
}

// ---------------- graph bounds (batch is sorted) ----------------
__global__ void graph_bounds(const int* __restrict__ batch, int* __restrict__ bounds) {
    int g = threadIdx.x;  // single block, 128 threads
    if (g < N_GRAPHS) {
        int lo = 0, hi = N_NODES;
        while (lo < hi) { int mid = (lo + hi) >> 1; if (batch[mid] < g) lo = mid + 1; else hi = mid; }
        bounds[g] = lo;
    }
    if (g == 0) bounds[N_GRAPHS] = N_NODES;
}

// ---------------- fused mean-pool + FC head ----------------
__global__ __launch_bounds__(256) void pool_fc(const float* __restrict__ x,
                                               const int* __restrict__ bounds,
                                               const float* __restrict__ Wfc,
                                               const float* __restrict__ bfc,
                                               float* __restrict__ out) {
    int g = blockIdx.x;
    int lo = bounds[g], hi = bounds[g + 1];
    int c = threadIdx.x;
    float s = 0.f;
    for (int n = lo; n < hi; ++n) s += x[(size_t)n * 256 + c];
    float inv = 1.0f / fmaxf((float)(hi - lo), 1.0f);
    __shared__ float pooled[256];
    pooled[c] = s * inv;
    __syncthreads();
    if (c < N_CLASSES) {
        float acc = bfc[c];
        for (int k = 0; k < 256; ++k) acc += pooled[k] * Wfc[k * N_CLASSES + c];
        out[g * N_CLASSES + c] = acc;
    }
}

extern "C" void kernel_launch(void* const* d_in, const int* in_sizes, int n_in,
                              void* d_out, int out_size, void* d_ws, size_t ws_size,
                              hipStream_t stream) {
    const float* emb  = (const float*)d_in[0];
    const int*   eidx = (const int*)d_in[1];
    const int*   batch= (const int*)d_in[2];
    const float* W1   = (const float*)d_in[3];
    const float* b1   = (const float*)d_in[4];
    const float* W2   = (const float*)d_in[5];
    const float* b2   = (const float*)d_in[6];
    const float* Wfc  = (const float*)d_in[7];
    const float* bfc  = (const float*)d_in[8];
    float* out = (float*)d_out;

    const int* src = eidx;
    const int* dst = eidx + N_EDGES;

    char* ws = (char*)d_ws;
    size_t off = 0;
    auto alloc = [&](size_t bytes) { void* p = ws + off; off += (bytes + 1023) & ~(size_t)1023; return p; };
    int*   rowcnt   = (int*)alloc(N_NODES * 4);
    int*   rowstart = (int*)alloc((N_NODES + 1) * 4);
    int*   cursor   = (int*)alloc(N_NODES * 4);
    int*   col      = (int*)alloc(N_EDGES * 4);
    float* dinv     = (float*)alloc(N_NODES * 4);
    int*   bounds   = (int*)alloc((N_GRAPHS + 1) * 4);
    float* bufA     = (float*)alloc((size_t)N_NODES * 256 * 4);
    float* bufB     = (float*)alloc((size_t)N_NODES * 256 * 4);

    const int NB = (N_NODES + 255) / 256;
    const int EBk = (N_EDGES + 255) / 256;
    const int AGG_B = (N_NODES * 64 + 255) / 256;  // 12500
    dim3 gemm_grid1((N_NODES + 63) / 64, 4);

    // CSR + norm
    zero_int<<<NB, 256, 0, stream>>>(rowcnt, N_NODES);
    hist_dst<<<EBk, 256, 0, stream>>>(dst, rowcnt);
    make_dinv<<<NB, 256, 0, stream>>>(rowcnt, dinv);
    scan_kernel<<<1, 1024, 0, stream>>>(rowcnt, rowstart, cursor);
    scatter_edges<<<EBk, 256, 0, stream>>>(src, dst, cursor, col);

    // conv1
    gemm_n256<<<gemm_grid1, 256, 0, stream>>>(emb, W1, bufA, N_NODES, IN_DIM);
    agg_csr<true><<<AGG_B, 256, 0, stream>>>(bufA, dinv, rowstart, col, b1, bufB);

    // conv2
    gemm_n256<<<gemm_grid1, 256, 0, stream>>>(bufB, W2, bufA, N_NODES, HIDDEN);
    agg_csr<false><<<AGG_B, 256, 0, stream>>>(bufA, dinv, rowstart, col, b2, bufB);

    // pool + head
    graph_bounds<<<1, 128, 0, stream>>>(batch, bounds);
    pool_fc<<<N_GRAPHS, 256, 0, stream>>>(bufB, bounds, Wfc, bfc, out);
}

// Round 8
// 690.482 us; speedup vs baseline: 9.1868x; 1.4161x over previous
//
#include <hip/hip_runtime.h>

#define N_NODES 50000
#define N_EDGES 800000
#define IN_DIM 768
#define HIDDEN 256
#define N_CLASSES 10
#define N_GRAPHS 128

typedef __attribute__((ext_vector_type(8))) short bf16x8;
typedef __attribute__((ext_vector_type(4))) float f32x4;

__device__ __forceinline__ float bf2f(unsigned short u) {
    union { unsigned int i; float f; } c; c.i = ((unsigned int)u) << 16; return c.f;
}
__device__ __forceinline__ unsigned short f2bf(float f) {
    unsigned int x = __float_as_uint(f);
    return (unsigned short)((x + 0x7fffu + ((x >> 16) & 1u)) >> 16);  // RNE
}

// ---------------- CSR build ----------------
__global__ void zero_int(int* p, int n) {
    int i = blockIdx.x * blockDim.x + threadIdx.x;
    if (i < n) p[i] = 0;
}

__global__ void hist_dst(const int* __restrict__ dst, int* __restrict__ cnt) {
    int e = blockIdx.x * blockDim.x + threadIdx.x;
    if (e < N_EDGES) atomicAdd(&cnt[dst[e]], 1);
}

__global__ void make_dinv(const int* __restrict__ cnt, float* __restrict__ dinv) {
    int i = blockIdx.x * blockDim.x + threadIdx.x;
    if (i < N_NODES) dinv[i] = rsqrtf(1.0f + (float)cnt[i]);  // +1 self-loop
}

// single-block exclusive scan (shfl-based, 3 barriers/chunk)
__global__ __launch_bounds__(1024) void scan_kernel(const int* __restrict__ cnt,
                                                    int* __restrict__ rowstart,
                                                    int* __restrict__ cursor) {
    __shared__ int wsum[16];
    __shared__ int chunk_carry;
    const int tid = threadIdx.x, lane = tid & 63, wid = tid >> 6;
    if (tid == 0) chunk_carry = 0;
    __syncthreads();
    for (int base = 0; base < N_NODES; base += 1024) {
        int i = base + tid;
        int v = (i < N_NODES) ? cnt[i] : 0;
        int s = v;
#pragma unroll
        for (int d = 1; d < 64; d <<= 1) { int t = __shfl_up(s, d); if (lane >= d) s += t; }
        if (lane == 63) wsum[wid] = s;
        __syncthreads();
        if (tid < 16) {
            int ww = wsum[tid];
#pragma unroll
            for (int d = 1; d < 16; d <<= 1) { int t = __shfl_up(ww, d); if (tid >= d) ww += t; }
            wsum[tid] = ww;
        }
        __syncthreads();
        int wpre = (wid == 0) ? 0 : wsum[wid - 1];
        int excl = chunk_carry + wpre + s - v;
        if (i < N_NODES) { rowstart[i] = excl; cursor[i] = excl; }
        int total = wsum[15];
        __syncthreads();
        if (tid == 0) chunk_carry += total;
        __syncthreads();
    }
    if (threadIdx.x == 0) rowstart[N_NODES] = chunk_carry;
}

__global__ void scatter_edges(const int* __restrict__ src, const int* __restrict__ dst,
                              int* __restrict__ cursor, int* __restrict__ col) {
    int e = blockIdx.x * blockDim.x + threadIdx.x;
    if (e >= N_EDGES) return;
    int d = dst[e];
    int pos = atomicAdd(&cursor[d], 1);
    col[pos] = src[e];
}

// ---------------- fp32 -> bf16 conversions ----------------
__global__ void f32_to_bf16(const float* __restrict__ in, unsigned short* __restrict__ out, int n8) {
    int i = blockIdx.x * blockDim.x + threadIdx.x;
    if (i >= n8) return;
    float4 v0 = *(const float4*)&in[(size_t)i * 8];
    float4 v1 = *(const float4*)&in[(size_t)i * 8 + 4];
    *(ushort4*)&out[(size_t)i * 8] =
        make_ushort4(f2bf(v0.x), f2bf(v0.y), f2bf(v0.z), f2bf(v0.w));
    *(ushort4*)&out[(size_t)i * 8 + 4] =
        make_ushort4(f2bf(v1.x), f2bf(v1.y), f2bf(v1.z), f2bf(v1.w));
}

// W [K][256] fp32 -> WT [256][K] bf16
__global__ void transpose_w_bf16(const float* __restrict__ W, unsigned short* __restrict__ WT, int K) {
    int k = blockIdx.x * 256 + threadIdx.x;
    int n = blockIdx.y;
    WT[(size_t)n * K + k] = f2bf(W[(size_t)k * 256 + n]);
}

// ---------------- MFMA GEMM: C[M,256](bf16) = A[M,K](bf16) * BT[256,K]^T ----
// tile 128x64, BK=64, 4 waves; XOR-swizzled LDS (g ^= row&7 on 16B granules);
// swapped-operand mfma(B,A) -> epilogue is row-contiguous.
template <int K>
__global__ __launch_bounds__(256) void gemm_mfma(const unsigned short* __restrict__ A,
                                                 const unsigned short* __restrict__ BT,
                                                 unsigned short* __restrict__ C, int M) {
    __shared__ uint4 sm[1536];  // 24 KB: As 16 KB ([128 rows][8 gran]), Bs 8 KB ([64][8])
    uint4* As = sm;
    uint4* Bs = sm + 1024;
    const int tid = threadIdx.x;
    const int lane = tid & 63, w = tid >> 6;
    const int lr = lane & 15, kg = lane >> 4;
    const int bm = blockIdx.x * 128;
    const int bn = blockIdx.y * 64;

    f32x4 acc[2][4] = {};
    uint4 ar[4], br[2];

    // prologue: load first K-tile into regs
#pragma unroll
    for (int i = 0; i < 4; ++i) {
        int gi = i * 256 + tid, r = gi >> 3, g = gi & 7;
        int rg = bm + r; rg = rg < M ? rg : M - 1;
        ar[i] = *(const uint4*)&A[(size_t)rg * K + g * 8];
    }
#pragma unroll
    for (int i = 0; i < 2; ++i) {
        int gi = i * 256 + tid, n = gi >> 3, g = gi & 7;
        br[i] = *(const uint4*)&BT[(size_t)(bn + n) * K + g * 8];
    }

    for (int k0 = 0; k0 < K; k0 += 64) {
        // stage regs -> LDS (swizzled)
#pragma unroll
        for (int i = 0; i < 4; ++i) {
            int gi = i * 256 + tid, r = gi >> 3, g = gi & 7;
            As[r * 8 + (g ^ (r & 7))] = ar[i];
        }
#pragma unroll
        for (int i = 0; i < 2; ++i) {
            int gi = i * 256 + tid, n = gi >> 3, g = gi & 7;
            Bs[n * 8 + (g ^ (n & 7))] = br[i];
        }
        __syncthreads();
        // prefetch next K-tile (overlaps MFMA phase)
        if (k0 + 64 < K) {
            const int k1 = k0 + 64;
#pragma unroll
            for (int i = 0; i < 4; ++i) {
                int gi = i * 256 + tid, r = gi >> 3, g = gi & 7;
                int rg = bm + r; rg = rg < M ? rg : M - 1;
                ar[i] = *(const uint4*)&A[(size_t)rg * K + k1 + g * 8];
            }
#pragma unroll
            for (int i = 0; i < 2; ++i) {
                int gi = i * 256 + tid, n = gi >> 3, g = gi & 7;
                br[i] = *(const uint4*)&BT[(size_t)(bn + n) * K + k1 + g * 8];
            }
        }
        // compute: wave w owns rows [32w, 32w+32)
#pragma unroll
        for (int h = 0; h < 2; ++h) {
            int r0 = 32 * w + lr, r1 = r0 + 16;
            bf16x8 a0 = *(const bf16x8*)&As[r0 * 8 + ((4 * h + kg) ^ (r0 & 7))];
            bf16x8 a1 = *(const bf16x8*)&As[r1 * 8 + ((4 * h + kg) ^ (r1 & 7))];
#pragma unroll
            for (int f = 0; f < 4; ++f) {
                int nr = 16 * f + lr;
                bf16x8 bf = *(const bf16x8*)&Bs[nr * 8 + ((4 * h + kg) ^ (nr & 7))];
                acc[0][f] = __builtin_amdgcn_mfma_f32_16x16x32_bf16(bf, a0, acc[0][f], 0, 0, 0);
                acc[1][f] = __builtin_amdgcn_mfma_f32_16x16x32_bf16(bf, a1, acc[1][f], 0, 0, 0);
            }
        }
        __syncthreads();
    }
    // epilogue: D'[n][m] layout -> lane&15 = out row, (lane>>4)*4+reg = out col
#pragma unroll
    for (int m = 0; m < 2; ++m) {
        int orow = bm + 32 * w + 16 * m + lr;
        if (orow < M) {
#pragma unroll
            for (int f = 0; f < 4; ++f) {
                ushort4 o = make_ushort4(f2bf(acc[m][f][0]), f2bf(acc[m][f][1]),
                                         f2bf(acc[m][f][2]), f2bf(acc[m][f][3]));
                *(ushort4*)&C[(size_t)orow * 256 + bn + 16 * f + 4 * kg] = o;
            }
        }
    }
}

// ---------------- CSR aggregation (bf16 gather, fp32 accum) ----------------
template <bool RELU, bool OUTBF>
__global__ __launch_bounds__(256) void agg_csr(const unsigned short* __restrict__ h,
                                               const float* __restrict__ dinv,
                                               const int* __restrict__ rowstart,
                                               const int* __restrict__ col,
                                               const float* __restrict__ bias,
                                               void* __restrict__ outv) {
    int node = (blockIdx.x * 256 + threadIdx.x) >> 6;
    if (node >= N_NODES) return;
    int lane = threadIdx.x & 63;

    float dd = dinv[node];
    float ww = dd * dd;
    ushort4 hv = *(const ushort4*)&h[(size_t)node * 256 + (lane << 2)];
    float a0 = bf2f(hv.x) * ww, a1 = bf2f(hv.y) * ww, a2 = bf2f(hv.z) * ww, a3 = bf2f(hv.w) * ww;

    int j = rowstart[node], jend = rowstart[node + 1];
    for (; j + 1 < jend; j += 2) {
        int sa = col[j], sb = col[j + 1];
        float na = dinv[sa] * dd, nb = dinv[sb] * dd;
        ushort4 va = *(const ushort4*)&h[(size_t)sa * 256 + (lane << 2)];
        ushort4 vb = *(const ushort4*)&h[(size_t)sb * 256 + (lane << 2)];
        a0 += bf2f(va.x) * na + bf2f(vb.x) * nb;
        a1 += bf2f(va.y) * na + bf2f(vb.y) * nb;
        a2 += bf2f(va.z) * na + bf2f(vb.z) * nb;
        a3 += bf2f(va.w) * na + bf2f(vb.w) * nb;
    }
    if (j < jend) {
        int sa = col[j];
        float na = dinv[sa] * dd;
        ushort4 va = *(const ushort4*)&h[(size_t)sa * 256 + (lane << 2)];
        a0 += bf2f(va.x) * na; a1 += bf2f(va.y) * na;
        a2 += bf2f(va.z) * na; a3 += bf2f(va.w) * na;
    }

    const float4 bb = *(const float4*)&bias[lane << 2];
    a0 += bb.x; a1 += bb.y; a2 += bb.z; a3 += bb.w;
    if (RELU) {
        a0 = fmaxf(a0, 0.f); a1 = fmaxf(a1, 0.f);
        a2 = fmaxf(a2, 0.f); a3 = fmaxf(a3, 0.f);
    }
    if (OUTBF) {
        *(ushort4*)((unsigned short*)outv + (size_t)node * 256 + (lane << 2)) =
            make_ushort4(f2bf(a0), f2bf(a1), f2bf(a2), f2bf(a3));
    } else {
        *(float4*)((float*)outv + (size_t)node * 256 + (lane << 2)) =
            make_float4(a0, a1, a2, a3);
    }
}

// ---------------- graph bounds (batch is sorted) ----------------
__global__ void graph_bounds(const int* __restrict__ batch, int* __restrict__ bounds) {
    int g = threadIdx.x;  // single block, 128 threads
    if (g < N_GRAPHS) {
        int lo = 0, hi = N_NODES;
        while (lo < hi) { int mid = (lo + hi) >> 1; if (batch[mid] < g) lo = mid + 1; else hi = mid; }
        bounds[g] = lo;
    }
    if (g == 0) bounds[N_GRAPHS] = N_NODES;
}

// ---------------- fused mean-pool + FC head ----------------
__global__ __launch_bounds__(256) void pool_fc(const float* __restrict__ x,
                                               const int* __restrict__ bounds,
                                               const float* __restrict__ Wfc,
                                               const float* __restrict__ bfc,
                                               float* __restrict__ out) {
    int g = blockIdx.x;
    int lo = bounds[g], hi = bounds[g + 1];
    int c = threadIdx.x;
    float s = 0.f;
    for (int n = lo; n < hi; ++n) s += x[(size_t)n * 256 + c];
    float inv = 1.0f / fmaxf((float)(hi - lo), 1.0f);
    __shared__ float pooled[256];
    pooled[c] = s * inv;
    __syncthreads();
    if (c < N_CLASSES) {
        float acc = bfc[c];
        for (int k = 0; k < 256; ++k) acc += pooled[k] * Wfc[k * N_CLASSES + c];
        out[g * N_CLASSES + c] = acc;
    }
}

extern "C" void kernel_launch(void* const* d_in, const int* in_sizes, int n_in,
                              void* d_out, int out_size, void* d_ws, size_t ws_size,
                              hipStream_t stream) {
    const float* emb  = (const float*)d_in[0];
    const int*   eidx = (const int*)d_in[1];
    const int*   batch= (const int*)d_in[2];
    const float* W1   = (const float*)d_in[3];
    const float* b1   = (const float*)d_in[4];
    const float* W2   = (const float*)d_in[5];
    const float* b2   = (const float*)d_in[6];
    const float* Wfc  = (const float*)d_in[7];
    const float* bfc  = (const float*)d_in[8];
    float* out = (float*)d_out;

    const int* src = eidx;
    const int* dst = eidx + N_EDGES;

    char* ws = (char*)d_ws;
    size_t off = 0;
    auto alloc = [&](size_t bytes) { void* p = ws + off; off += (bytes + 1023) & ~(size_t)1023; return p; };
    int*   rowcnt   = (int*)alloc(N_NODES * 4);
    int*   rowstart = (int*)alloc((N_NODES + 1) * 4);
    int*   cursor   = (int*)alloc(N_NODES * 4);
    int*   col      = (int*)alloc(N_EDGES * 4);
    float* dinv     = (float*)alloc(N_NODES * 4);
    int*   bounds   = (int*)alloc((N_GRAPHS + 1) * 4);
    unsigned short* W1T = (unsigned short*)alloc((size_t)HIDDEN * IN_DIM * 2);   // [256][768]
    unsigned short* W2T = (unsigned short*)alloc((size_t)HIDDEN * HIDDEN * 2);   // [256][256]
    unsigned short* bufH = (unsigned short*)alloc((size_t)N_NODES * 256 * 2);    // h (bf16)
    // region R (76.8 MB): emb_bf16 during conv1; later x1 (bf16, 25.6 MB) + x2 (f32, 51.2 MB)
    unsigned short* R = (unsigned short*)alloc((size_t)N_NODES * IN_DIM * 2);
    unsigned short* emb_bf = R;
    unsigned short* x1 = R;                                        // [50000][256] bf16
    float* x2 = (float*)(R + (size_t)N_NODES * 256);               // [50000][256] f32

    const int NB = (N_NODES + 255) / 256;
    const int EBk = (N_EDGES + 255) / 256;
    const int AGG_B = (N_NODES * 64 + 255) / 256;  // 12500
    dim3 gemm_grid((N_NODES + 127) / 128, 4);      // (391, 4)

    // CSR + norm
    zero_int<<<NB, 256, 0, stream>>>(rowcnt, N_NODES);
    hist_dst<<<EBk, 256, 0, stream>>>(dst, rowcnt);
    make_dinv<<<NB, 256, 0, stream>>>(rowcnt, dinv);
    scan_kernel<<<1, 1024, 0, stream>>>(rowcnt, rowstart, cursor);
    scatter_edges<<<EBk, 256, 0, stream>>>(src, dst, cursor, col);

    // bf16 conversions
    f32_to_bf16<<<(N_NODES * IN_DIM / 8 + 255) / 256, 256, 0, stream>>>(emb, emb_bf, N_NODES * IN_DIM / 8);
    transpose_w_bf16<<<dim3(IN_DIM / 256, HIDDEN), 256, 0, stream>>>(W1, W1T, IN_DIM);
    transpose_w_bf16<<<dim3(HIDDEN / 256, HIDDEN), 256, 0, stream>>>(W2, W2T, HIDDEN);

    // conv1: h1 = emb_bf @ W1  (bf16 MFMA), then agg -> x1 (bf16, relu)
    gemm_mfma<IN_DIM><<<gemm_grid, 256, 0, stream>>>(emb_bf, W1T, bufH, N_NODES);
    agg_csr<true, true><<<AGG_B, 256, 0, stream>>>(bufH, dinv, rowstart, col, b1, x1);

    // conv2: h2 = x1 @ W2, then agg -> x2 (f32)
    gemm_mfma<HIDDEN><<<gemm_grid, 256, 0, stream>>>(x1, W2T, bufH, N_NODES);
    agg_csr<false, false><<<AGG_B, 256, 0, stream>>>(bufH, dinv, rowstart, col, b2, x2);

    // pool + head
    graph_bounds<<<1, 128, 0, stream>>>(batch, bounds);
    pool_fc<<<N_GRAPHS, 256, 0, stream>>>(x2, bounds, Wfc, bfc, out);
}

// Round 9
// 546.478 us; speedup vs baseline: 11.6077x; 1.2635x over previous
//
#include <hip/hip_runtime.h>

#define N_NODES 50000
#define N_EDGES 800000
#define IN_DIM 768
#define HIDDEN 256
#define N_CLASSES 10
#define N_GRAPHS 128

typedef __attribute__((ext_vector_type(8))) short bf16x8;
typedef __attribute__((ext_vector_type(4))) float f32x4;

__device__ __forceinline__ float bf2f(unsigned short u) {
    union { unsigned int i; float f; } c; c.i = ((unsigned int)u) << 16; return c.f;
}
__device__ __forceinline__ unsigned short f2bf(float f) {
    unsigned int x = __float_as_uint(f);
    return (unsigned short)((x + 0x7fffu + ((x >> 16) & 1u)) >> 16);  // RNE
}

// async global->LDS, 16B per lane; LDS dest = uniform base + lane*16
__device__ __forceinline__ void gload16(const void* g, void* l) {
    __builtin_amdgcn_global_load_lds((const __attribute__((address_space(1))) void*)g,
                                     (__attribute__((address_space(3))) void*)l, 16, 0, 0);
}

// ---------------- CSR build ----------------
__global__ void zero_int(int* p, int n) {
    int i = blockIdx.x * blockDim.x + threadIdx.x;
    if (i < n) p[i] = 0;
}

__global__ void hist_dst(const int* __restrict__ dst, int* __restrict__ cnt) {
    int e = blockIdx.x * blockDim.x + threadIdx.x;
    if (e < N_EDGES) atomicAdd(&cnt[dst[e]], 1);
}

__global__ void make_dinv(const int* __restrict__ cnt, float* __restrict__ dinv) {
    int i = blockIdx.x * blockDim.x + threadIdx.x;
    if (i < N_NODES) dinv[i] = rsqrtf(1.0f + (float)cnt[i]);  // +1 self-loop
}

// single-block exclusive scan (shfl-based)
__global__ __launch_bounds__(1024) void scan_kernel(const int* __restrict__ cnt,
                                                    int* __restrict__ rowstart,
                                                    int* __restrict__ cursor) {
    __shared__ int wsum[16];
    __shared__ int chunk_carry;
    const int tid = threadIdx.x, lane = tid & 63, wid = tid >> 6;
    if (tid == 0) chunk_carry = 0;
    __syncthreads();
    for (int base = 0; base < N_NODES; base += 1024) {
        int i = base + tid;
        int v = (i < N_NODES) ? cnt[i] : 0;
        int s = v;
#pragma unroll
        for (int d = 1; d < 64; d <<= 1) { int t = __shfl_up(s, d); if (lane >= d) s += t; }
        if (lane == 63) wsum[wid] = s;
        __syncthreads();
        if (tid < 16) {
            int ww = wsum[tid];
#pragma unroll
            for (int d = 1; d < 16; d <<= 1) { int t = __shfl_up(ww, d); if (tid >= d) ww += t; }
            wsum[tid] = ww;
        }
        __syncthreads();
        int wpre = (wid == 0) ? 0 : wsum[wid - 1];
        int excl = chunk_carry + wpre + s - v;
        if (i < N_NODES) { rowstart[i] = excl; cursor[i] = excl; }
        int total = wsum[15];
        __syncthreads();
        if (tid == 0) chunk_carry += total;
        __syncthreads();
    }
    if (threadIdx.x == 0) rowstart[N_NODES] = chunk_carry;
}

__global__ void scatter_edges(const int* __restrict__ src, const int* __restrict__ dst,
                              int* __restrict__ cursor, int* __restrict__ col) {
    int e = blockIdx.x * blockDim.x + threadIdx.x;
    if (e >= N_EDGES) return;
    int d = dst[e];
    int pos = atomicAdd(&cursor[d], 1);
    col[pos] = src[e];
}

// ---------------- fp32 -> bf16 conversions ----------------
__global__ void f32_to_bf16(const float* __restrict__ in, unsigned short* __restrict__ out, int n8) {
    int i = blockIdx.x * blockDim.x + threadIdx.x;
    if (i >= n8) return;
    float4 v0 = *(const float4*)&in[(size_t)i * 8];
    float4 v1 = *(const float4*)&in[(size_t)i * 8 + 4];
    *(ushort4*)&out[(size_t)i * 8] =
        make_ushort4(f2bf(v0.x), f2bf(v0.y), f2bf(v0.z), f2bf(v0.w));
    *(ushort4*)&out[(size_t)i * 8 + 4] =
        make_ushort4(f2bf(v1.x), f2bf(v1.y), f2bf(v1.z), f2bf(v1.w));
}

// W [K][256] fp32 -> WT [256][K] bf16
__global__ void transpose_w_bf16(const float* __restrict__ W, unsigned short* __restrict__ WT, int K) {
    int k = blockIdx.x * 256 + threadIdx.x;
    int n = blockIdx.y;
    WT[(size_t)n * K + k] = f2bf(W[(size_t)k * 256 + n]);
}

// ---------------- MFMA GEMM: C[M,256](bf16) = A[M,K](bf16) * BT[256,K]^T ----
// tile 128x256 (full N), BK=64, 4 waves, grid (ceil(M/128), 1) -> A fetched once.
// Staging: global_load_lds w=16, linear LDS dest, PRE-SWIZZLED per-lane global
// source (granule g fetches src granule g^(row&7)); reads apply the same XOR.
template <int K>
__global__ __launch_bounds__(256) void gemm_mfma(const unsigned short* __restrict__ A,
                                                 const unsigned short* __restrict__ BT,
                                                 unsigned short* __restrict__ C, int M) {
    __shared__ uint4 sm[3072];  // 48 KB: As [128][8] granules (16 KB), Bs [256][8] (32 KB)
    uint4* As = sm;
    uint4* Bs = sm + 1024;
    const int tid = threadIdx.x;
    const int lane = tid & 63, w = tid >> 6;
    const int lr = lane & 15, kg = lane >> 4;
    const int bm = blockIdx.x * 128;

    f32x4 acc[2][16] = {};

    for (int k0 = 0; k0 < K; k0 += 64) {
        // stage A: 1024 granules, wave w handles [w*256, w*256+256), 4 instrs
#pragma unroll
        for (int i = 0; i < 4; ++i) {
            int glin = w * 256 + i * 64 + lane;       // per-lane granule index
            int r = glin >> 3, g = glin & 7;
            int gs = g ^ (r & 7);                      // pre-swizzled source granule
            int rg = bm + r; rg = rg < M ? rg : M - 1;
            gload16(&A[(size_t)rg * K + k0 + gs * 8], &As[w * 256 + i * 64]);
        }
        // stage B: 2048 granules, wave w handles [w*512, w*512+512), 8 instrs
#pragma unroll
        for (int i = 0; i < 8; ++i) {
            int glin = w * 512 + i * 64 + lane;
            int n = glin >> 3, g = glin & 7;
            int gs = g ^ (n & 7);
            gload16(&BT[(size_t)n * K + k0 + gs * 8], &Bs[w * 512 + i * 64]);
        }
        __syncthreads();  // drains vmcnt (gload_lds) + lgkm

        // compute: wave w owns rows [32w, 32w+32), all 256 cols
#pragma unroll
        for (int h = 0; h < 2; ++h) {
            int r0 = 32 * w + lr, r1 = r0 + 16;
            bf16x8 a0 = *(const bf16x8*)&As[r0 * 8 + ((4 * h + kg) ^ (r0 & 7))];
            bf16x8 a1 = *(const bf16x8*)&As[r1 * 8 + ((4 * h + kg) ^ (r1 & 7))];
#pragma unroll
            for (int f = 0; f < 16; ++f) {
                int nr = 16 * f + lr;
                bf16x8 bf = *(const bf16x8*)&Bs[nr * 8 + ((4 * h + kg) ^ (nr & 7))];
                acc[0][f] = __builtin_amdgcn_mfma_f32_16x16x32_bf16(bf, a0, acc[0][f], 0, 0, 0);
                acc[1][f] = __builtin_amdgcn_mfma_f32_16x16x32_bf16(bf, a1, acc[1][f], 0, 0, 0);
            }
        }
        __syncthreads();
    }
    // epilogue: swapped layout -> lane lr = out row, col = 16f + 4kg
#pragma unroll
    for (int m = 0; m < 2; ++m) {
        int orow = bm + 32 * w + 16 * m + lr;
        if (orow < M) {
#pragma unroll
            for (int f = 0; f < 16; ++f) {
                ushort4 o = make_ushort4(f2bf(acc[m][f][0]), f2bf(acc[m][f][1]),
                                         f2bf(acc[m][f][2]), f2bf(acc[m][f][3]));
                *(ushort4*)&C[(size_t)orow * 256 + 16 * f + 4 * kg] = o;
            }
        }
    }
}

// ---------------- CSR aggregation (bf16 gather, fp32 accum) ----------------
template <bool RELU, bool OUTBF>
__global__ __launch_bounds__(256) void agg_csr(const unsigned short* __restrict__ h,
                                               const float* __restrict__ dinv,
                                               const int* __restrict__ rowstart,
                                               const int* __restrict__ col,
                                               const float* __restrict__ bias,
                                               void* __restrict__ outv) {
    int node = (blockIdx.x * 256 + threadIdx.x) >> 6;
    if (node >= N_NODES) return;
    int lane = threadIdx.x & 63;

    float dd = dinv[node];
    float ww = dd * dd;
    ushort4 hv = *(const ushort4*)&h[(size_t)node * 256 + (lane << 2)];
    float a0 = bf2f(hv.x) * ww, a1 = bf2f(hv.y) * ww, a2 = bf2f(hv.z) * ww, a3 = bf2f(hv.w) * ww;

    int j = rowstart[node], jend = rowstart[node + 1];
    for (; j + 1 < jend; j += 2) {
        int sa = col[j], sb = col[j + 1];
        float na = dinv[sa] * dd, nb = dinv[sb] * dd;
        ushort4 va = *(const ushort4*)&h[(size_t)sa * 256 + (lane << 2)];
        ushort4 vb = *(const ushort4*)&h[(size_t)sb * 256 + (lane << 2)];
        a0 += bf2f(va.x) * na + bf2f(vb.x) * nb;
        a1 += bf2f(va.y) * na + bf2f(vb.y) * nb;
        a2 += bf2f(va.z) * na + bf2f(vb.z) * nb;
        a3 += bf2f(va.w) * na + bf2f(vb.w) * nb;
    }
    if (j < jend) {
        int sa = col[j];
        float na = dinv[sa] * dd;
        ushort4 va = *(const ushort4*)&h[(size_t)sa * 256 + (lane << 2)];
        a0 += bf2f(va.x) * na; a1 += bf2f(va.y) * na;
        a2 += bf2f(va.z) * na; a3 += bf2f(va.w) * na;
    }

    const float4 bb = *(const float4*)&bias[lane << 2];
    a0 += bb.x; a1 += bb.y; a2 += bb.z; a3 += bb.w;
    if (RELU) {
        a0 = fmaxf(a0, 0.f); a1 = fmaxf(a1, 0.f);
        a2 = fmaxf(a2, 0.f); a3 = fmaxf(a3, 0.f);
    }
    if (OUTBF) {
        *(ushort4*)((unsigned short*)outv + (size_t)node * 256 + (lane << 2)) =
            make_ushort4(f2bf(a0), f2bf(a1), f2bf(a2), f2bf(a3));
    } else {
        *(float4*)((float*)outv + (size_t)node * 256 + (lane << 2)) =
            make_float4(a0, a1, a2, a3);
    }
}

// ---------------- graph bounds (batch is sorted) ----------------
__global__ void graph_bounds(const int* __restrict__ batch, int* __restrict__ bounds) {
    int g = threadIdx.x;  // single block, 128 threads
    if (g < N_GRAPHS) {
        int lo = 0, hi = N_NODES;
        while (lo < hi) { int mid = (lo + hi) >> 1; if (batch[mid] < g) lo = mid + 1; else hi = mid; }
        bounds[g] = lo;
    }
    if (g == 0) bounds[N_GRAPHS] = N_NODES;
}

// ---------------- fused mean-pool + FC head ----------------
__global__ __launch_bounds__(256) void pool_fc(const float* __restrict__ x,
                                               const int* __restrict__ bounds,
                                               const float* __restrict__ Wfc,
                                               const float* __restrict__ bfc,
                                               float* __restrict__ out) {
    int g = blockIdx.x;
    int lo = bounds[g], hi = bounds[g + 1];
    int c = threadIdx.x;
    float s = 0.f;
    for (int n = lo; n < hi; ++n) s += x[(size_t)n * 256 + c];
    float inv = 1.0f / fmaxf((float)(hi - lo), 1.0f);
    __shared__ float pooled[256];
    pooled[c] = s * inv;
    __syncthreads();
    if (c < N_CLASSES) {
        float acc = bfc[c];
        for (int k = 0; k < 256; ++k) acc += pooled[k] * Wfc[k * N_CLASSES + c];
        out[g * N_CLASSES + c] = acc;
    }
}

extern "C" void kernel_launch(void* const* d_in, const int* in_sizes, int n_in,
                              void* d_out, int out_size, void* d_ws, size_t ws_size,
                              hipStream_t stream) {
    const float* emb  = (const float*)d_in[0];
    const int*   eidx = (const int*)d_in[1];
    const int*   batch= (const int*)d_in[2];
    const float* W1   = (const float*)d_in[3];
    const float* b1   = (const float*)d_in[4];
    const float* W2   = (const float*)d_in[5];
    const float* b2   = (const float*)d_in[6];
    const float* Wfc  = (const float*)d_in[7];
    const float* bfc  = (const float*)d_in[8];
    float* out = (float*)d_out;

    const int* src = eidx;
    const int* dst = eidx + N_EDGES;

    char* ws = (char*)d_ws;
    size_t off = 0;
    auto alloc = [&](size_t bytes) { void* p = ws + off; off += (bytes + 1023) & ~(size_t)1023; return p; };
    int*   rowcnt   = (int*)alloc(N_NODES * 4);
    int*   rowstart = (int*)alloc((N_NODES + 1) * 4);
    int*   cursor   = (int*)alloc(N_NODES * 4);
    int*   col      = (int*)alloc(N_EDGES * 4);
    float* dinv     = (float*)alloc(N_NODES * 4);
    int*   bounds   = (int*)alloc((N_GRAPHS + 1) * 4);
    unsigned short* W1T = (unsigned short*)alloc((size_t)HIDDEN * IN_DIM * 2);   // [256][768]
    unsigned short* W2T = (unsigned short*)alloc((size_t)HIDDEN * HIDDEN * 2);   // [256][256]
    unsigned short* bufH = (unsigned short*)alloc((size_t)N_NODES * 256 * 2);    // h (bf16)
    // region R (76.8 MB): emb_bf16 during conv1; later x1 (bf16) + x2 (f32)
    unsigned short* R = (unsigned short*)alloc((size_t)N_NODES * IN_DIM * 2);
    unsigned short* emb_bf = R;
    unsigned short* x1 = R;                                        // [50000][256] bf16
    float* x2 = (float*)(R + (size_t)N_NODES * 256);               // [50000][256] f32

    const int NB = (N_NODES + 255) / 256;
    const int EBk = (N_EDGES + 255) / 256;
    const int AGG_B = (N_NODES * 64 + 255) / 256;  // 12500
    dim3 gemm_grid((N_NODES + 127) / 128, 1);      // 391 blocks, full N per block

    // CSR + norm
    zero_int<<<NB, 256, 0, stream>>>(rowcnt, N_NODES);
    hist_dst<<<EBk, 256, 0, stream>>>(dst, rowcnt);
    make_dinv<<<NB, 256, 0, stream>>>(rowcnt, dinv);
    scan_kernel<<<1, 1024, 0, stream>>>(rowcnt, rowstart, cursor);
    scatter_edges<<<EBk, 256, 0, stream>>>(src, dst, cursor, col);

    // bf16 conversions
    f32_to_bf16<<<(N_NODES * IN_DIM / 8 + 255) / 256, 256, 0, stream>>>(emb, emb_bf, N_NODES * IN_DIM / 8);
    transpose_w_bf16<<<dim3(IN_DIM / 256, HIDDEN), 256, 0, stream>>>(W1, W1T, IN_DIM);
    transpose_w_bf16<<<dim3(HIDDEN / 256, HIDDEN), 256, 0, stream>>>(W2, W2T, HIDDEN);

    // conv1: h1 = emb_bf @ W1  (bf16 MFMA), then agg -> x1 (bf16, relu)
    gemm_mfma<IN_DIM><<<gemm_grid, 256, 0, stream>>>(emb_bf, W1T, bufH, N_NODES);
    agg_csr<true, true><<<AGG_B, 256, 0, stream>>>(bufH, dinv, rowstart, col, b1, x1);

    // conv2: h2 = x1 @ W2, then agg -> x2 (f32)
    gemm_mfma<HIDDEN><<<gemm_grid, 256, 0, stream>>>(x1, W2T, bufH, N_NODES);
    agg_csr<false, false><<<AGG_B, 256, 0, stream>>>(bufH, dinv, rowstart, col, b2, x2);

    // pool + head
    graph_bounds<<<1, 128, 0, stream>>>(batch, bounds);
    pool_fc<<<N_GRAPHS, 256, 0, stream>>>(x2, bounds, Wfc, bfc, out);
}

// Round 11
// 458.627 us; speedup vs baseline: 13.8311x; 1.1916x over previous
//
#include <hip/hip_runtime.h>

#define N_NODES 50000
#define N_EDGES 800000
#define IN_DIM 768
#define HIDDEN 256
#define N_CLASSES 10
#define N_GRAPHS 128

typedef __attribute__((ext_vector_type(8))) short bf16x8;
typedef __attribute__((ext_vector_type(4))) float f32x4;

__device__ __forceinline__ float bf2f(unsigned short u) {
    union { unsigned int i; float f; } c; c.i = ((unsigned int)u) << 16; return c.f;
}
__device__ __forceinline__ unsigned short f2bf(float f) {
    unsigned int x = __float_as_uint(f);
    return (unsigned short)((x + 0x7fffu + ((x >> 16) & 1u)) >> 16);  // RNE
}

// async global->LDS, 16B per lane; LDS dest = uniform base + lane*16
__device__ __forceinline__ void gload16(const void* g, void* l) {
    __builtin_amdgcn_global_load_lds((const __attribute__((address_space(1))) void*)g,
                                     (__attribute__((address_space(3))) void*)l, 16, 0, 0);
}

// ---------------- CSR build ----------------
__global__ void zero_int(int* p, int n) {
    int i = blockIdx.x * blockDim.x + threadIdx.x;
    if (i < n) p[i] = 0;
}

__global__ void zero_f32(float* p, int n) {
    int i = blockIdx.x * blockDim.x + threadIdx.x;
    if (i < n) p[i] = 0.f;
}

__global__ void hist_dst(const int* __restrict__ dst, int* __restrict__ cnt) {
    int e = blockIdx.x * blockDim.x + threadIdx.x;
    if (e < N_EDGES) atomicAdd(&cnt[dst[e]], 1);
}

__global__ void make_dinv(const int* __restrict__ cnt, float* __restrict__ dinv) {
    int i = blockIdx.x * blockDim.x + threadIdx.x;
    if (i < N_NODES) dinv[i] = rsqrtf(1.0f + (float)cnt[i]);  // +1 self-loop
}

// single-block exclusive scan (shfl-based)
__global__ __launch_bounds__(1024) void scan_kernel(const int* __restrict__ cnt,
                                                    int* __restrict__ rowstart,
                                                    int* __restrict__ cursor) {
    __shared__ int wsum[16];
    __shared__ int chunk_carry;
    const int tid = threadIdx.x, lane = tid & 63, wid = tid >> 6;
    if (tid == 0) chunk_carry = 0;
    __syncthreads();
    for (int base = 0; base < N_NODES; base += 1024) {
        int i = base + tid;
        int v = (i < N_NODES) ? cnt[i] : 0;
        int s = v;
#pragma unroll
        for (int d = 1; d < 64; d <<= 1) { int t = __shfl_up(s, d); if (lane >= d) s += t; }
        if (lane == 63) wsum[wid] = s;
        __syncthreads();
        if (tid < 16) {
            int ww = wsum[tid];
#pragma unroll
            for (int d = 1; d < 16; d <<= 1) { int t = __shfl_up(ww, d); if (tid >= d) ww += t; }
            wsum[tid] = ww;
        }
        __syncthreads();
        int wpre = (wid == 0) ? 0 : wsum[wid - 1];
        int excl = chunk_carry + wpre + s - v;
        if (i < N_NODES) { rowstart[i] = excl; cursor[i] = excl; }
        int total = wsum[15];
        __syncthreads();
        if (tid == 0) chunk_carry += total;
        __syncthreads();
    }
    if (threadIdx.x == 0) rowstart[N_NODES] = chunk_carry;
}

__global__ void scatter_edges(const int* __restrict__ src, const int* __restrict__ dst,
                              int* __restrict__ cursor, int* __restrict__ col) {
    int e = blockIdx.x * blockDim.x + threadIdx.x;
    if (e >= N_EDGES) return;
    int d = dst[e];
    int pos = atomicAdd(&cursor[d], 1);
    col[pos] = src[e];
}

// ---------------- fp32 -> bf16 conversions ----------------
__global__ void f32_to_bf16(const float* __restrict__ in, unsigned short* __restrict__ out, int n8) {
    int i = blockIdx.x * blockDim.x + threadIdx.x;
    if (i >= n8) return;
    float4 v0 = *(const float4*)&in[(size_t)i * 8];
    float4 v1 = *(const float4*)&in[(size_t)i * 8 + 4];
    *(ushort4*)&out[(size_t)i * 8] =
        make_ushort4(f2bf(v0.x), f2bf(v0.y), f2bf(v0.z), f2bf(v0.w));
    *(ushort4*)&out[(size_t)i * 8 + 4] =
        make_ushort4(f2bf(v1.x), f2bf(v1.y), f2bf(v1.z), f2bf(v1.w));
}

// W [K][256] fp32 -> WT [256][K] bf16
__global__ void transpose_w_bf16(const float* __restrict__ W, unsigned short* __restrict__ WT, int K) {
    int k = blockIdx.x * 256 + threadIdx.x;
    int n = blockIdx.y;
    WT[(size_t)n * K + k] = f2bf(W[(size_t)k * 256 + n]);
}

// ---------------- MFMA GEMM: C[M,256](bf16) = A[M,K](bf16) * BT[256,K]^T ----
// tile 128x256 (full N), BK=64, 4 waves, grid (ceil(M/128), 1) -> A fetched once.
// Staging: global_load_lds w=16, linear LDS dest, PRE-SWIZZLED per-lane global
// source (granule g fetches src granule g^(row&7)); reads apply the same XOR.
template <int K>
__global__ __launch_bounds__(256) void gemm_mfma(const unsigned short* __restrict__ A,
                                                 const unsigned short* __restrict__ BT,
                                                 unsigned short* __restrict__ C, int M) {
    __shared__ uint4 sm[3072];  // 48 KB: As [128][8] granules (16 KB), Bs [256][8] (32 KB)
    uint4* As = sm;
    uint4* Bs = sm + 1024;
    const int tid = threadIdx.x;
    const int lane = tid & 63, w = tid >> 6;
    const int lr = lane & 15, kg = lane >> 4;
    const int bm = blockIdx.x * 128;

    f32x4 acc[2][16] = {};

    for (int k0 = 0; k0 < K; k0 += 64) {
        // stage A: 1024 granules, wave w handles [w*256, w*256+256), 4 instrs
#pragma unroll
        for (int i = 0; i < 4; ++i) {
            int glin = w * 256 + i * 64 + lane;       // per-lane granule index
            int r = glin >> 3, g = glin & 7;
            int gs = g ^ (r & 7);                      // pre-swizzled source granule
            int rg = bm + r; rg = rg < M ? rg : M - 1;
            gload16(&A[(size_t)rg * K + k0 + gs * 8], &As[w * 256 + i * 64]);
        }
        // stage B: 2048 granules, wave w handles [w*512, w*512+512), 8 instrs
#pragma unroll
        for (int i = 0; i < 8; ++i) {
            int glin = w * 512 + i * 64 + lane;
            int n = glin >> 3, g = glin & 7;
            int gs = g ^ (n & 7);
            gload16(&BT[(size_t)n * K + k0 + gs * 8], &Bs[w * 512 + i * 64]);
        }
        __syncthreads();  // drains vmcnt (gload_lds) + lgkm

        // compute: wave w owns rows [32w, 32w+32), all 256 cols
#pragma unroll
        for (int h = 0; h < 2; ++h) {
            int r0 = 32 * w + lr, r1 = r0 + 16;
            bf16x8 a0 = *(const bf16x8*)&As[r0 * 8 + ((4 * h + kg) ^ (r0 & 7))];
            bf16x8 a1 = *(const bf16x8*)&As[r1 * 8 + ((4 * h + kg) ^ (r1 & 7))];
#pragma unroll
            for (int f = 0; f < 16; ++f) {
                int nr = 16 * f + lr;
                bf16x8 bf = *(const bf16x8*)&Bs[nr * 8 + ((4 * h + kg) ^ (nr & 7))];
                acc[0][f] = __builtin_amdgcn_mfma_f32_16x16x32_bf16(bf, a0, acc[0][f], 0, 0, 0);
                acc[1][f] = __builtin_amdgcn_mfma_f32_16x16x32_bf16(bf, a1, acc[1][f], 0, 0, 0);
            }
        }
        __syncthreads();
    }
    // epilogue: swapped layout -> lane lr = out row, col = 16f + 4kg
#pragma unroll
    for (int m = 0; m < 2; ++m) {
        int orow = bm + 32 * w + 16 * m + lr;
        if (orow < M) {
#pragma unroll
            for (int f = 0; f < 16; ++f) {
                ushort4 o = make_ushort4(f2bf(acc[m][f][0]), f2bf(acc[m][f][1]),
                                         f2bf(acc[m][f][2]), f2bf(acc[m][f][3]));
                *(ushort4*)&C[(size_t)orow * 256 + 16 * f + 4 * kg] = o;
            }
        }
    }
}

// ---------------- CSR aggregation (bf16 gather, fp32 accum) ----------------
template <bool RELU, bool OUTBF>
__global__ __launch_bounds__(256) void agg_csr(const unsigned short* __restrict__ h,
                                               const float* __restrict__ dinv,
                                               const int* __restrict__ rowstart,
                                               const int* __restrict__ col,
                                               const float* __restrict__ bias,
                                               void* __restrict__ outv) {
    int node = (blockIdx.x * 256 + threadIdx.x) >> 6;
    if (node >= N_NODES) return;
    int lane = threadIdx.x & 63;

    float dd = dinv[node];
    float ww = dd * dd;
    ushort4 hv = *(const ushort4*)&h[(size_t)node * 256 + (lane << 2)];
    float a0 = bf2f(hv.x) * ww, a1 = bf2f(hv.y) * ww, a2 = bf2f(hv.z) * ww, a3 = bf2f(hv.w) * ww;

    int j = rowstart[node], jend = rowstart[node + 1];
    for (; j + 1 < jend; j += 2) {
        int sa = col[j], sb = col[j + 1];
        float na = dinv[sa] * dd, nb = dinv[sb] * dd;
        ushort4 va = *(const ushort4*)&h[(size_t)sa * 256 + (lane << 2)];
        ushort4 vb = *(const ushort4*)&h[(size_t)sb * 256 + (lane << 2)];
        a0 += bf2f(va.x) * na + bf2f(vb.x) * nb;
        a1 += bf2f(va.y) * na + bf2f(vb.y) * nb;
        a2 += bf2f(va.z) * na + bf2f(vb.z) * nb;
        a3 += bf2f(va.w) * na + bf2f(vb.w) * nb;
    }
    if (j < jend) {
        int sa = col[j];
        float na = dinv[sa] * dd;
        ushort4 va = *(const ushort4*)&h[(size_t)sa * 256 + (lane << 2)];
        a0 += bf2f(va.x) * na; a1 += bf2f(va.y) * na;
        a2 += bf2f(va.z) * na; a3 += bf2f(va.w) * na;
    }

    const float4 bb = *(const float4*)&bias[lane << 2];
    a0 += bb.x; a1 += bb.y; a2 += bb.z; a3 += bb.w;
    if (RELU) {
        a0 = fmaxf(a0, 0.f); a1 = fmaxf(a1, 0.f);
        a2 = fmaxf(a2, 0.f); a3 = fmaxf(a3, 0.f);
    }
    if (OUTBF) {
        *(ushort4*)((unsigned short*)outv + (size_t)node * 256 + (lane << 2)) =
            make_ushort4(f2bf(a0), f2bf(a1), f2bf(a2), f2bf(a3));
    } else {
        *(float4*)((float*)outv + (size_t)node * 256 + (lane << 2)) =
            make_float4(a0, a1, a2, a3);
    }
}

// ---------------- graph bounds (batch is sorted) ----------------
__global__ void graph_bounds(const int* __restrict__ batch, int* __restrict__ bounds) {
    int g = threadIdx.x;  // single block, 128 threads
    if (g < N_GRAPHS) {
        int lo = 0, hi = N_NODES;
        while (lo < hi) { int mid = (lo + hi) >> 1; if (batch[mid] < g) lo = mid + 1; else hi = mid; }
        bounds[g] = lo;
    }
    if (g == 0) bounds[N_GRAPHS] = N_NODES;
}

// ---------------- parallel segmented pooling ----------------
// 1021 blocks x 256 threads; block owns nodes [blk*49, ...); thread owns channel c.
// batch sorted -> register-accumulate, flush per graph transition via atomicAdd.
#define POOL_CHUNK 49
__global__ __launch_bounds__(256) void pool_partial(const float* __restrict__ x,
                                                    const int* __restrict__ batch,
                                                    float* __restrict__ gsum) {
    int lo = blockIdx.x * POOL_CHUNK;
    if (lo >= N_NODES) return;
    int hi = lo + POOL_CHUNK; if (hi > N_NODES) hi = N_NODES;
    int c = threadIdx.x;
    int g = batch[lo];
    float acc = 0.f;
    for (int n = lo; n < hi; ++n) {
        int gn = batch[n];
        if (gn != g) { atomicAdd(&gsum[g * 256 + c], acc); acc = 0.f; g = gn; }
        acc += x[(size_t)n * 256 + c];
    }
    atomicAdd(&gsum[g * 256 + c], acc);
}

// ---------------- FC head over pooled sums ----------------
__global__ __launch_bounds__(256) void fc_head(const float* __restrict__ gsum,
                                               const int* __restrict__ bounds,
                                               const float* __restrict__ Wfc,
                                               const float* __restrict__ bfc,
                                               float* __restrict__ out) {
    int g = blockIdx.x;
    int c = threadIdx.x;
    float inv = 1.0f / fmaxf((float)(bounds[g + 1] - bounds[g]), 1.0f);
    __shared__ float pooled[256];
    pooled[c] = gsum[(size_t)g * 256 + c] * inv;
    __syncthreads();
    if (c < N_CLASSES) {
        float acc = bfc[c];
        for (int k = 0; k < 256; ++k) acc += pooled[k] * Wfc[k * N_CLASSES + c];
        out[g * N_CLASSES + c] = acc;
    }
}

extern "C" void kernel_launch(void* const* d_in, const int* in_sizes, int n_in,
                              void* d_out, int out_size, void* d_ws, size_t ws_size,
                              hipStream_t stream) {
    const float* emb  = (const float*)d_in[0];
    const int*   eidx = (const int*)d_in[1];
    const int*   batch= (const int*)d_in[2];
    const float* W1   = (const float*)d_in[3];
    const float* b1   = (const float*)d_in[4];
    const float* W2   = (const float*)d_in[5];
    const float* b2   = (const float*)d_in[6];
    const float* Wfc  = (const float*)d_in[7];
    const float* bfc  = (const float*)d_in[8];
    float* out = (float*)d_out;

    const int* src = eidx;
    const int* dst = eidx + N_EDGES;

    char* ws = (char*)d_ws;
    size_t off = 0;
    auto alloc = [&](size_t bytes) { void* p = ws + off; off += (bytes + 1023) & ~(size_t)1023; return p; };
    int*   rowcnt   = (int*)alloc(N_NODES * 4);
    int*   rowstart = (int*)alloc((N_NODES + 1) * 4);
    int*   cursor   = (int*)alloc(N_NODES * 4);
    int*   col      = (int*)alloc(N_EDGES * 4);
    float* dinv     = (float*)alloc(N_NODES * 4);
    int*   bounds   = (int*)alloc((N_GRAPHS + 1) * 4);
    float* gsum     = (float*)alloc((size_t)N_GRAPHS * 256 * 4);
    unsigned short* W1T = (unsigned short*)alloc((size_t)HIDDEN * IN_DIM * 2);   // [256][768]
    unsigned short* W2T = (unsigned short*)alloc((size_t)HIDDEN * HIDDEN * 2);   // [256][256]
    unsigned short* bufH = (unsigned short*)alloc((size_t)N_NODES * 256 * 2);    // h (bf16)
    // region R (76.8 MB): emb_bf16 during conv1; later x1 (bf16) + x2 (f32)
    unsigned short* R = (unsigned short*)alloc((size_t)N_NODES * IN_DIM * 2);
    unsigned short* emb_bf = R;
    unsigned short* x1 = R;                                        // [50000][256] bf16
    float* x2 = (float*)(R + (size_t)N_NODES * 256);               // [50000][256] f32

    const int NB = (N_NODES + 255) / 256;
    const int EBk = (N_EDGES + 255) / 256;
    const int AGG_B = (N_NODES * 64 + 255) / 256;  // 12500
    dim3 gemm_grid((N_NODES + 127) / 128, 1);      // 391 blocks, full N per block
    const int POOL_B = (N_NODES + POOL_CHUNK - 1) / POOL_CHUNK;  // 1021

    // CSR + norm
    zero_int<<<NB, 256, 0, stream>>>(rowcnt, N_NODES);
    hist_dst<<<EBk, 256, 0, stream>>>(dst, rowcnt);
    make_dinv<<<NB, 256, 0, stream>>>(rowcnt, dinv);
    scan_kernel<<<1, 1024, 0, stream>>>(rowcnt, rowstart, cursor);
    scatter_edges<<<EBk, 256, 0, stream>>>(src, dst, cursor, col);
    graph_bounds<<<1, 128, 0, stream>>>(batch, bounds);
    zero_f32<<<(N_GRAPHS * 256 + 255) / 256, 256, 0, stream>>>(gsum, N_GRAPHS * 256);

    // bf16 conversions
    f32_to_bf16<<<(N_NODES * IN_DIM / 8 + 255) / 256, 256, 0, stream>>>(emb, emb_bf, N_NODES * IN_DIM / 8);
    transpose_w_bf16<<<dim3(IN_DIM / 256, HIDDEN), 256, 0, stream>>>(W1, W1T, IN_DIM);
    transpose_w_bf16<<<dim3(HIDDEN / 256, HIDDEN), 256, 0, stream>>>(W2, W2T, HIDDEN);

    // conv1: h1 = emb_bf @ W1  (bf16 MFMA), then agg -> x1 (bf16, relu)
    gemm_mfma<IN_DIM><<<gemm_grid, 256, 0, stream>>>(emb_bf, W1T, bufH, N_NODES);
    agg_csr<true, true><<<AGG_B, 256, 0, stream>>>(bufH, dinv, rowstart, col, b1, x1);

    // conv2: h2 = x1 @ W2, then agg -> x2 (f32)
    gemm_mfma<HIDDEN><<<gemm_grid, 256, 0, stream>>>(x1, W2T, bufH, N_NODES);
    agg_csr<false, false><<<AGG_B, 256, 0, stream>>>(bufH, dinv, rowstart, col, b2, x2);

    // pool + head
    pool_partial<<<POOL_B, 256, 0, stream>>>(x2, batch, gsum);
    fc_head<<<N_GRAPHS, 256, 0, stream>>>(gsum, bounds, Wfc, bfc, out);
}

// Round 12
// 450.135 us; speedup vs baseline: 14.0921x; 1.0189x over previous
//
#include <hip/hip_runtime.h>

#define N_NODES 50000
#define N_EDGES 800000
#define IN_DIM 768
#define HIDDEN 256
#define N_CLASSES 10
#define N_GRAPHS 128

typedef __attribute__((ext_vector_type(8))) short bf16x8;
typedef __attribute__((ext_vector_type(4))) float f32x4;
typedef __attribute__((ext_vector_type(8))) unsigned short u16x8;

__device__ __forceinline__ float bf2f(unsigned short u) {
    union { unsigned int i; float f; } c; c.i = ((unsigned int)u) << 16; return c.f;
}
__device__ __forceinline__ unsigned short f2bf(float f) {
    unsigned int x = __float_as_uint(f);
    return (unsigned short)((x + 0x7fffu + ((x >> 16) & 1u)) >> 16);  // RNE
}

// async global->LDS, 16B per lane; LDS dest = uniform base + lane*16
__device__ __forceinline__ void gload16(const void* g, void* l) {
    __builtin_amdgcn_global_load_lds((const __attribute__((address_space(1))) void*)g,
                                     (__attribute__((address_space(3))) void*)l, 16, 0, 0);
}

// ---------------- CSR build ----------------
__global__ void zero_int(int* p, int n) {
    int i = blockIdx.x * blockDim.x + threadIdx.x;
    if (i < n) p[i] = 0;
}

__global__ void zero_f32(float* p, int n) {
    int i = blockIdx.x * blockDim.x + threadIdx.x;
    if (i < n) p[i] = 0.f;
}

__global__ void hist_dst(const int* __restrict__ dst, int* __restrict__ cnt) {
    int e = blockIdx.x * blockDim.x + threadIdx.x;
    if (e < N_EDGES) atomicAdd(&cnt[dst[e]], 1);
}

// single-block exclusive scan (shfl-based) + fused dinv = rsqrt(1+cnt)
__global__ __launch_bounds__(1024) void scan_kernel(const int* __restrict__ cnt,
                                                    int* __restrict__ rowstart,
                                                    int* __restrict__ cursor,
                                                    float* __restrict__ dinv) {
    __shared__ int wsum[16];
    __shared__ int chunk_carry;
    const int tid = threadIdx.x, lane = tid & 63, wid = tid >> 6;
    if (tid == 0) chunk_carry = 0;
    __syncthreads();
    for (int base = 0; base < N_NODES; base += 1024) {
        int i = base + tid;
        int v = (i < N_NODES) ? cnt[i] : 0;
        if (i < N_NODES) dinv[i] = rsqrtf(1.0f + (float)v);
        int s = v;
#pragma unroll
        for (int d = 1; d < 64; d <<= 1) { int t = __shfl_up(s, d); if (lane >= d) s += t; }
        if (lane == 63) wsum[wid] = s;
        __syncthreads();
        if (tid < 16) {
            int ww = wsum[tid];
#pragma unroll
            for (int d = 1; d < 16; d <<= 1) { int t = __shfl_up(ww, d); if (tid >= d) ww += t; }
            wsum[tid] = ww;
        }
        __syncthreads();
        int wpre = (wid == 0) ? 0 : wsum[wid - 1];
        int excl = chunk_carry + wpre + s - v;
        if (i < N_NODES) { rowstart[i] = excl; cursor[i] = excl; }
        int total = wsum[15];
        __syncthreads();
        if (tid == 0) chunk_carry += total;
        __syncthreads();
    }
    if (threadIdx.x == 0) rowstart[N_NODES] = chunk_carry;
}

__global__ void scatter_edges(const int* __restrict__ src, const int* __restrict__ dst,
                              int* __restrict__ cursor, int* __restrict__ col) {
    int e = blockIdx.x * blockDim.x + threadIdx.x;
    if (e >= N_EDGES) return;
    int d = dst[e];
    int pos = atomicAdd(&cursor[d], 1);
    col[pos] = src[e];
}

// ---------------- W [K][256] fp32 -> WT [256][K] bf16, LDS-tiled ----------------
__global__ __launch_bounds__(256) void transpose_w_bf16(const float* __restrict__ W,
                                                        unsigned short* __restrict__ WT, int K) {
    __shared__ float t[32][33];
    int tx = threadIdx.x & 31, ty = threadIdx.x >> 5;  // 8 row-groups
    int k0 = blockIdx.x * 32, n0 = blockIdx.y * 32;
#pragma unroll
    for (int i = 0; i < 4; ++i) {
        int k = k0 + ty + i * 8;
        t[ty + i * 8][tx] = W[(size_t)k * 256 + n0 + tx];
    }
    __syncthreads();
#pragma unroll
    for (int i = 0; i < 4; ++i) {
        int n = n0 + ty + i * 8;
        WT[(size_t)n * K + k0 + tx] = f2bf(t[tx][ty + i * 8]);
    }
}

// ---------------- MFMA GEMM: C[M,256](bf16) = A[M,K] * BT[256,K]^T ----
// tile 128x256 (full N), BK=64, 4 waves, grid (ceil(M/128), 1).
// CVT=false: A is bf16, staged via global_load_lds (linear dest, pre-swizzled src).
// CVT=true:  A is f32, reg-staged + converted + swizzled ds_write_b128.
// LDS slot [r][g] holds source granule g^(r&7); reads apply the same XOR.
template <int K, bool CVT>
__global__ __launch_bounds__(256) void gemm_mfma(const void* __restrict__ Av,
                                                 const unsigned short* __restrict__ BT,
                                                 unsigned short* __restrict__ C, int M) {
    __shared__ uint4 sm[3072];  // 48 KB: As [128][8] granules (16 KB), Bs [256][8] (32 KB)
    uint4* As = sm;
    uint4* Bs = sm + 1024;
    const int tid = threadIdx.x;
    const int lane = tid & 63, w = tid >> 6;
    const int lr = lane & 15, kg = lane >> 4;
    const int bm = blockIdx.x * 128;

    f32x4 acc[2][16] = {};

    for (int k0 = 0; k0 < K; k0 += 64) {
        // stage A
        if constexpr (CVT) {
            const float* Af = (const float*)Av;
#pragma unroll
            for (int i = 0; i < 4; ++i) {
                int glin = i * 256 + tid, r = glin >> 3, g = glin & 7;
                int gs = g ^ (r & 7);
                int rg = bm + r; rg = rg < M ? rg : M - 1;
                const float* p = &Af[(size_t)rg * K + k0 + gs * 8];
                float4 u = *(const float4*)p;
                float4 v = *(const float4*)(p + 4);
                u16x8 o;
                o[0] = f2bf(u.x); o[1] = f2bf(u.y); o[2] = f2bf(u.z); o[3] = f2bf(u.w);
                o[4] = f2bf(v.x); o[5] = f2bf(v.y); o[6] = f2bf(v.z); o[7] = f2bf(v.w);
                *(u16x8*)&As[r * 8 + g] = o;
            }
        } else {
            const unsigned short* Ab = (const unsigned short*)Av;
#pragma unroll
            for (int i = 0; i < 4; ++i) {
                int glin = w * 256 + i * 64 + lane;
                int r = glin >> 3, g = glin & 7;
                int gs = g ^ (r & 7);
                int rg = bm + r; rg = rg < M ? rg : M - 1;
                gload16(&Ab[(size_t)rg * K + k0 + gs * 8], &As[w * 256 + i * 64]);
            }
        }
        // stage B: 2048 granules via global_load_lds
#pragma unroll
        for (int i = 0; i < 8; ++i) {
            int glin = w * 512 + i * 64 + lane;
            int n = glin >> 3, g = glin & 7;
            int gs = g ^ (n & 7);
            gload16(&BT[(size_t)n * K + k0 + gs * 8], &Bs[w * 512 + i * 64]);
        }
        __syncthreads();  // drains vmcnt + lgkm

        // compute: wave w owns rows [32w, 32w+32), all 256 cols
#pragma unroll
        for (int h = 0; h < 2; ++h) {
            int r0 = 32 * w + lr, r1 = r0 + 16;
            bf16x8 a0 = *(const bf16x8*)&As[r0 * 8 + ((4 * h + kg) ^ (r0 & 7))];
            bf16x8 a1 = *(const bf16x8*)&As[r1 * 8 + ((4 * h + kg) ^ (r1 & 7))];
#pragma unroll
            for (int f = 0; f < 16; ++f) {
                int nr = 16 * f + lr;
                bf16x8 bf = *(const bf16x8*)&Bs[nr * 8 + ((4 * h + kg) ^ (nr & 7))];
                acc[0][f] = __builtin_amdgcn_mfma_f32_16x16x32_bf16(bf, a0, acc[0][f], 0, 0, 0);
                acc[1][f] = __builtin_amdgcn_mfma_f32_16x16x32_bf16(bf, a1, acc[1][f], 0, 0, 0);
            }
        }
        __syncthreads();
    }
    // epilogue: swapped layout -> lane lr = out row, col = 16f + 4kg
#pragma unroll
    for (int m = 0; m < 2; ++m) {
        int orow = bm + 32 * w + 16 * m + lr;
        if (orow < M) {
#pragma unroll
            for (int f = 0; f < 16; ++f) {
                ushort4 o = make_ushort4(f2bf(acc[m][f][0]), f2bf(acc[m][f][1]),
                                         f2bf(acc[m][f][2]), f2bf(acc[m][f][3]));
                *(ushort4*)&C[(size_t)orow * 256 + 16 * f + 4 * kg] = o;
            }
        }
    }
}

// ---------------- CSR aggregation: 16B gathers, 2 edges per wave-step ------
// one wave per dst node; lanes 0-31 = edge j (cols sl*8..+8), lanes 32-63 = edge j+1.
// cross-half merge via shfl_xor(32) at the end.
template <bool RELU, bool OUTBF>
__global__ __launch_bounds__(256) void agg_csr(const unsigned short* __restrict__ h,
                                               const float* __restrict__ dinv,
                                               const int* __restrict__ rowstart,
                                               const int* __restrict__ col,
                                               const float* __restrict__ bias,
                                               void* __restrict__ outv) {
    int node = (blockIdx.x * 256 + threadIdx.x) >> 6;
    if (node >= N_NODES) return;
    const int lane = threadIdx.x & 63;
    const int half = lane >> 5, sl = lane & 31;

    float dd = dinv[node];
    float acc[8] = {};

    // self term (half 0 only contributes; half 1 loads same line, weight 0)
    {
        u16x8 hv = *(const u16x8*)&h[(size_t)node * 256 + sl * 8];
        float wgt = half ? 0.f : dd * dd;
#pragma unroll
        for (int i = 0; i < 8; ++i) acc[i] += bf2f(hv[i]) * wgt;
    }

    int j0 = rowstart[node], jend = rowstart[node + 1];
    for (int j = j0; j < jend; j += 2) {
        int sidx = j + half;
        bool p = sidx < jend;
        int s = p ? col[sidx] : node;
        float nrm = p ? dinv[s] * dd : 0.f;
        u16x8 v = *(const u16x8*)&h[(size_t)s * 256 + sl * 8];
#pragma unroll
        for (int i = 0; i < 8; ++i) acc[i] += bf2f(v[i]) * nrm;
    }

    // merge halves
#pragma unroll
    for (int i = 0; i < 8; ++i) acc[i] += __shfl_xor(acc[i], 32);

    if (half == 0) {
        float4 b0 = *(const float4*)&bias[sl * 8];
        float4 b1 = *(const float4*)&bias[sl * 8 + 4];
        acc[0] += b0.x; acc[1] += b0.y; acc[2] += b0.z; acc[3] += b0.w;
        acc[4] += b1.x; acc[5] += b1.y; acc[6] += b1.z; acc[7] += b1.w;
        if (RELU) {
#pragma unroll
            for (int i = 0; i < 8; ++i) acc[i] = fmaxf(acc[i], 0.f);
        }
        if (OUTBF) {
            u16x8 o;
#pragma unroll
            for (int i = 0; i < 8; ++i) o[i] = f2bf(acc[i]);
            *(u16x8*)((unsigned short*)outv + (size_t)node * 256 + sl * 8) = o;
        } else {
            float* ob = (float*)outv + (size_t)node * 256 + sl * 8;
            *(float4*)ob = make_float4(acc[0], acc[1], acc[2], acc[3]);
            *(float4*)(ob + 4) = make_float4(acc[4], acc[5], acc[6], acc[7]);
        }
    }
}

// ---------------- parallel segmented pooling ----------------
#define POOL_CHUNK 49
__global__ __launch_bounds__(256) void pool_partial(const float* __restrict__ x,
                                                    const int* __restrict__ batch,
                                                    float* __restrict__ gsum) {
    int lo = blockIdx.x * POOL_CHUNK;
    if (lo >= N_NODES) return;
    int hi = lo + POOL_CHUNK; if (hi > N_NODES) hi = N_NODES;
    int c = threadIdx.x;
    int g = batch[lo];
    float acc = 0.f;
    for (int n = lo; n < hi; ++n) {
        int gn = batch[n];
        if (gn != g) { atomicAdd(&gsum[g * 256 + c], acc); acc = 0.f; g = gn; }
        acc += x[(size_t)n * 256 + c];
    }
    atomicAdd(&gsum[g * 256 + c], acc);
}

// ---------------- FC head (graph bounds via in-kernel binary search) --------
__global__ __launch_bounds__(256) void fc_head(const float* __restrict__ gsum,
                                               const int* __restrict__ batch,
                                               const float* __restrict__ Wfc,
                                               const float* __restrict__ bfc,
                                               float* __restrict__ out) {
    int g = blockIdx.x;
    int c = threadIdx.x;
    int lo = 0, hi = N_NODES;
    while (lo < hi) { int m = (lo + hi) >> 1; if (batch[m] < g) lo = m + 1; else hi = m; }
    int lo2 = lo, hi2 = N_NODES;
    while (lo2 < hi2) { int m = (lo2 + hi2) >> 1; if (batch[m] < g + 1) lo2 = m + 1; else hi2 = m; }
    float inv = 1.0f / fmaxf((float)(lo2 - lo), 1.0f);
    __shared__ float pooled[256];
    pooled[c] = gsum[(size_t)g * 256 + c] * inv;
    __syncthreads();
    if (c < N_CLASSES) {
        float acc = bfc[c];
        for (int k = 0; k < 256; ++k) acc += pooled[k] * Wfc[k * N_CLASSES + c];
        out[g * N_CLASSES + c] = acc;
    }
}

extern "C" void kernel_launch(void* const* d_in, const int* in_sizes, int n_in,
                              void* d_out, int out_size, void* d_ws, size_t ws_size,
                              hipStream_t stream) {
    const float* emb  = (const float*)d_in[0];
    const int*   eidx = (const int*)d_in[1];
    const int*   batch= (const int*)d_in[2];
    const float* W1   = (const float*)d_in[3];
    const float* b1   = (const float*)d_in[4];
    const float* W2   = (const float*)d_in[5];
    const float* b2   = (const float*)d_in[6];
    const float* Wfc  = (const float*)d_in[7];
    const float* bfc  = (const float*)d_in[8];
    float* out = (float*)d_out;

    const int* src = eidx;
    const int* dst = eidx + N_EDGES;

    char* ws = (char*)d_ws;
    size_t off = 0;
    auto alloc = [&](size_t bytes) { void* p = ws + off; off += (bytes + 1023) & ~(size_t)1023; return p; };
    int*   rowcnt   = (int*)alloc(N_NODES * 4);
    int*   rowstart = (int*)alloc((N_NODES + 1) * 4);
    int*   cursor   = (int*)alloc(N_NODES * 4);
    int*   col      = (int*)alloc(N_EDGES * 4);
    float* dinv     = (float*)alloc(N_NODES * 4);
    float* gsum     = (float*)alloc((size_t)N_GRAPHS * 256 * 4);
    unsigned short* W1T = (unsigned short*)alloc((size_t)HIDDEN * IN_DIM * 2);   // [256][768]
    unsigned short* W2T = (unsigned short*)alloc((size_t)HIDDEN * HIDDEN * 2);   // [256][256]
    unsigned short* bufH = (unsigned short*)alloc((size_t)N_NODES * 256 * 2);    // h (bf16)
    unsigned short* x1 = (unsigned short*)alloc((size_t)N_NODES * 256 * 2);      // bf16
    float* x2 = (float*)alloc((size_t)N_NODES * 256 * 4);                        // f32

    const int NB = (N_NODES + 255) / 256;
    const int EBk = (N_EDGES + 255) / 256;
    const int AGG_B = (N_NODES * 64 + 255) / 256;  // 12500
    dim3 gemm_grid((N_NODES + 127) / 128, 1);      // 391 blocks, full N per block
    const int POOL_B = (N_NODES + POOL_CHUNK - 1) / POOL_CHUNK;  // 1021

    // CSR + norm
    zero_int<<<NB, 256, 0, stream>>>(rowcnt, N_NODES);
    hist_dst<<<EBk, 256, 0, stream>>>(dst, rowcnt);
    scan_kernel<<<1, 1024, 0, stream>>>(rowcnt, rowstart, cursor, dinv);
    scatter_edges<<<EBk, 256, 0, stream>>>(src, dst, cursor, col);
    zero_f32<<<(N_GRAPHS * 256 + 255) / 256, 256, 0, stream>>>(gsum, N_GRAPHS * 256);

    // weight transposes (bf16)
    transpose_w_bf16<<<dim3(IN_DIM / 32, 8), 256, 0, stream>>>(W1, W1T, IN_DIM);
    transpose_w_bf16<<<dim3(HIDDEN / 32, 8), 256, 0, stream>>>(W2, W2T, HIDDEN);

    // conv1: h1 = emb @ W1 (f32 A converted in-staging), then agg -> x1 (bf16, relu)
    gemm_mfma<IN_DIM, true><<<gemm_grid, 256, 0, stream>>>(emb, W1T, bufH, N_NODES);
    agg_csr<true, true><<<AGG_B, 256, 0, stream>>>(bufH, dinv, rowstart, col, b1, x1);

    // conv2: h2 = x1 @ W2, then agg -> x2 (f32)
    gemm_mfma<HIDDEN, false><<<gemm_grid, 256, 0, stream>>>(x1, W2T, bufH, N_NODES);
    agg_csr<false, false><<<AGG_B, 256, 0, stream>>>(bufH, dinv, rowstart, col, b2, x2);

    // pool + head
    pool_partial<<<POOL_B, 256, 0, stream>>>(x2, batch, gsum);
    fc_head<<<N_GRAPHS, 256, 0, stream>>>(gsum, batch, Wfc, bfc, out);
}

// Round 13
// 418.475 us; speedup vs baseline: 15.1582x; 1.0757x over previous
//
#include <hip/hip_runtime.h>

#define N_NODES 50000
#define N_EDGES 800000
#define IN_DIM 768
#define HIDDEN 256
#define N_CLASSES 10
#define N_GRAPHS 128

typedef __attribute__((ext_vector_type(8))) short bf16x8;
typedef __attribute__((ext_vector_type(4))) float f32x4;
typedef __attribute__((ext_vector_type(8))) unsigned short u16x8;

__device__ __forceinline__ float bf2f(unsigned short u) {
    union { unsigned int i; float f; } c; c.i = ((unsigned int)u) << 16; return c.f;
}
__device__ __forceinline__ unsigned short f2bf(float f) {
    unsigned int x = __float_as_uint(f);
    return (unsigned short)((x + 0x7fffu + ((x >> 16) & 1u)) >> 16);  // RNE
}

// async global->LDS, 16B per lane; LDS dest = uniform base + lane*16
__device__ __forceinline__ void gload16(const void* g, void* l) {
    __builtin_amdgcn_global_load_lds((const __attribute__((address_space(1))) void*)g,
                                     (__attribute__((address_space(3))) void*)l, 16, 0, 0);
}

// ---------------- CSR build ----------------
__global__ void zero_int(int* p, int n) {
    int i = blockIdx.x * blockDim.x + threadIdx.x;
    if (i < n) p[i] = 0;
}

__global__ void zero_f32(float* p, int n) {
    int i = blockIdx.x * blockDim.x + threadIdx.x;
    if (i < n) p[i] = 0.f;
}

__global__ void hist_dst(const int* __restrict__ dst, int* __restrict__ cnt) {
    int e = blockIdx.x * blockDim.x + threadIdx.x;
    if (e < N_EDGES) atomicAdd(&cnt[dst[e]], 1);
}

// single-block exclusive scan (shfl-based) + fused dinv = rsqrt(1+cnt)
__global__ __launch_bounds__(1024) void scan_kernel(const int* __restrict__ cnt,
                                                    int* __restrict__ rowstart,
                                                    int* __restrict__ cursor,
                                                    float* __restrict__ dinv) {
    __shared__ int wsum[16];
    __shared__ int chunk_carry;
    const int tid = threadIdx.x, lane = tid & 63, wid = tid >> 6;
    if (tid == 0) chunk_carry = 0;
    __syncthreads();
    for (int base = 0; base < N_NODES; base += 1024) {
        int i = base + tid;
        int v = (i < N_NODES) ? cnt[i] : 0;
        if (i < N_NODES) dinv[i] = rsqrtf(1.0f + (float)v);
        int s = v;
#pragma unroll
        for (int d = 1; d < 64; d <<= 1) { int t = __shfl_up(s, d); if (lane >= d) s += t; }
        if (lane == 63) wsum[wid] = s;
        __syncthreads();
        if (tid < 16) {
            int ww = wsum[tid];
#pragma unroll
            for (int d = 1; d < 16; d <<= 1) { int t = __shfl_up(ww, d); if (tid >= d) ww += t; }
            wsum[tid] = ww;
        }
        __syncthreads();
        int wpre = (wid == 0) ? 0 : wsum[wid - 1];
        int excl = chunk_carry + wpre + s - v;
        if (i < N_NODES) { rowstart[i] = excl; cursor[i] = excl; }
        int total = wsum[15];
        __syncthreads();
        if (tid == 0) chunk_carry += total;
        __syncthreads();
    }
    if (threadIdx.x == 0) rowstart[N_NODES] = chunk_carry;
}

__global__ void scatter_edges(const int* __restrict__ src, const int* __restrict__ dst,
                              int* __restrict__ cursor, int* __restrict__ col) {
    int e = blockIdx.x * blockDim.x + threadIdx.x;
    if (e >= N_EDGES) return;
    int d = dst[e];
    int pos = atomicAdd(&cursor[d], 1);
    col[pos] = src[e];
}

// ---------------- W [K][256] fp32 -> WT [256][K] bf16, LDS-tiled ----------------
__global__ __launch_bounds__(256) void transpose_w_bf16(const float* __restrict__ W,
                                                        unsigned short* __restrict__ WT, int K) {
    __shared__ float t[32][33];
    int tx = threadIdx.x & 31, ty = threadIdx.x >> 5;  // 8 row-groups
    int k0 = blockIdx.x * 32, n0 = blockIdx.y * 32;
#pragma unroll
    for (int i = 0; i < 4; ++i) {
        int k = k0 + ty + i * 8;
        t[ty + i * 8][tx] = W[(size_t)k * 256 + n0 + tx];
    }
    __syncthreads();
#pragma unroll
    for (int i = 0; i < 4; ++i) {
        int n = n0 + ty + i * 8;
        WT[(size_t)n * K + k0 + tx] = f2bf(t[tx][ty + i * 8]);
    }
}

// ---------------- MFMA GEMM: C[M,256](bf16) = A[M,K] * BT[256,K]^T ----
// tile 64x256 (full N), BK=64, 4 waves (wave w owns rows [16w,16w+16)),
// grid (ceil(M/64), 1) -> ~3 blocks/CU for inter-block latency hiding.
// CVT=false: A bf16 staged via global_load_lds (linear dest, pre-swizzled src).
// CVT=true:  A f32, reg-staged + converted + swizzled ds_write.
// LDS slot [r][g] holds source granule g^(r&7); reads apply the same XOR.
template <int K, bool CVT>
__global__ __launch_bounds__(256, 4) void gemm_mfma(const void* __restrict__ Av,
                                                    const unsigned short* __restrict__ BT,
                                                    unsigned short* __restrict__ C, int M) {
    __shared__ uint4 sm[2560];  // 40 KB: As [64][8] granules (8 KB), Bs [256][8] (32 KB)
    uint4* As = sm;
    uint4* Bs = sm + 512;
    const int tid = threadIdx.x;
    const int lane = tid & 63, w = tid >> 6;
    const int lr = lane & 15, kg = lane >> 4;
    const int bm = blockIdx.x * 64;

    f32x4 acc[16] = {};

    for (int k0 = 0; k0 < K; k0 += 64) {
        // stage A: 512 granules (64 rows x 8)
        if constexpr (CVT) {
            const float* Af = (const float*)Av;
#pragma unroll
            for (int i = 0; i < 2; ++i) {
                int glin = i * 256 + tid, r = glin >> 3, g = glin & 7;
                int gs = g ^ (r & 7);
                int rg = bm + r; rg = rg < M ? rg : M - 1;
                const float* p = &Af[(size_t)rg * K + k0 + gs * 8];
                float4 u = *(const float4*)p;
                float4 v = *(const float4*)(p + 4);
                u16x8 o;
                o[0] = f2bf(u.x); o[1] = f2bf(u.y); o[2] = f2bf(u.z); o[3] = f2bf(u.w);
                o[4] = f2bf(v.x); o[5] = f2bf(v.y); o[6] = f2bf(v.z); o[7] = f2bf(v.w);
                *(u16x8*)&As[r * 8 + g] = o;
            }
        } else {
            const unsigned short* Ab = (const unsigned short*)Av;
#pragma unroll
            for (int i = 0; i < 2; ++i) {
                int glin = w * 128 + i * 64 + lane;
                int r = glin >> 3, g = glin & 7;
                int gs = g ^ (r & 7);
                int rg = bm + r; rg = rg < M ? rg : M - 1;
                gload16(&Ab[(size_t)rg * K + k0 + gs * 8], &As[w * 128 + i * 64]);
            }
        }
        // stage B: 2048 granules via global_load_lds
#pragma unroll
        for (int i = 0; i < 8; ++i) {
            int glin = w * 512 + i * 64 + lane;
            int n = glin >> 3, g = glin & 7;
            int gs = g ^ (n & 7);
            gload16(&BT[(size_t)n * K + k0 + gs * 8], &Bs[w * 512 + i * 64]);
        }
        __syncthreads();  // drains vmcnt + lgkm

        // compute: wave w owns rows [16w, 16w+16), all 256 cols
#pragma unroll
        for (int h = 0; h < 2; ++h) {
            int r0 = 16 * w + lr;
            bf16x8 a0 = *(const bf16x8*)&As[r0 * 8 + ((4 * h + kg) ^ (r0 & 7))];
#pragma unroll
            for (int f = 0; f < 16; ++f) {
                int nr = 16 * f + lr;
                bf16x8 bf = *(const bf16x8*)&Bs[nr * 8 + ((4 * h + kg) ^ (nr & 7))];
                acc[f] = __builtin_amdgcn_mfma_f32_16x16x32_bf16(bf, a0, acc[f], 0, 0, 0);
            }
        }
        __syncthreads();
    }
    // epilogue: swapped layout -> lane lr = out row, col = 16f + 4kg
    int orow = bm + 16 * w + lr;
    if (orow < M) {
#pragma unroll
        for (int f = 0; f < 16; ++f) {
            ushort4 o = make_ushort4(f2bf(acc[f][0]), f2bf(acc[f][1]),
                                     f2bf(acc[f][2]), f2bf(acc[f][3]));
            *(ushort4*)&C[(size_t)orow * 256 + 16 * f + 4 * kg] = o;
        }
    }
}

// ---------------- CSR aggregation: 16B gathers, 2 edges per wave-step ------
template <bool RELU, bool OUTBF>
__global__ __launch_bounds__(256) void agg_csr(const unsigned short* __restrict__ h,
                                               const float* __restrict__ dinv,
                                               const int* __restrict__ rowstart,
                                               const int* __restrict__ col,
                                               const float* __restrict__ bias,
                                               void* __restrict__ outv) {
    int node = (blockIdx.x * 256 + threadIdx.x) >> 6;
    if (node >= N_NODES) return;
    const int lane = threadIdx.x & 63;
    const int half = lane >> 5, sl = lane & 31;

    float dd = dinv[node];
    float acc[8] = {};

    // self term (half 0 only contributes; half 1 loads same line, weight 0)
    {
        u16x8 hv = *(const u16x8*)&h[(size_t)node * 256 + sl * 8];
        float wgt = half ? 0.f : dd * dd;
#pragma unroll
        for (int i = 0; i < 8; ++i) acc[i] += bf2f(hv[i]) * wgt;
    }

    int j0 = rowstart[node], jend = rowstart[node + 1];
    for (int j = j0; j < jend; j += 2) {
        int sidx = j + half;
        bool p = sidx < jend;
        int s = p ? col[sidx] : node;
        float nrm = p ? dinv[s] * dd : 0.f;
        u16x8 v = *(const u16x8*)&h[(size_t)s * 256 + sl * 8];
#pragma unroll
        for (int i = 0; i < 8; ++i) acc[i] += bf2f(v[i]) * nrm;
    }

    // merge halves
#pragma unroll
    for (int i = 0; i < 8; ++i) acc[i] += __shfl_xor(acc[i], 32);

    if (half == 0) {
        float4 b0 = *(const float4*)&bias[sl * 8];
        float4 b1 = *(const float4*)&bias[sl * 8 + 4];
        acc[0] += b0.x; acc[1] += b0.y; acc[2] += b0.z; acc[3] += b0.w;
        acc[4] += b1.x; acc[5] += b1.y; acc[6] += b1.z; acc[7] += b1.w;
        if (RELU) {
#pragma unroll
            for (int i = 0; i < 8; ++i) acc[i] = fmaxf(acc[i], 0.f);
        }
        if (OUTBF) {
            u16x8 o;
#pragma unroll
            for (int i = 0; i < 8; ++i) o[i] = f2bf(acc[i]);
            *(u16x8*)((unsigned short*)outv + (size_t)node * 256 + sl * 8) = o;
        } else {
            float* ob = (float*)outv + (size_t)node * 256 + sl * 8;
            *(float4*)ob = make_float4(acc[0], acc[1], acc[2], acc[3]);
            *(float4*)(ob + 4) = make_float4(acc[4], acc[5], acc[6], acc[7]);
        }
    }
}

// ---------------- parallel segmented pooling ----------------
#define POOL_CHUNK 49
__global__ __launch_bounds__(256) void pool_partial(const float* __restrict__ x,
                                                    const int* __restrict__ batch,
                                                    float* __restrict__ gsum) {
    int lo = blockIdx.x * POOL_CHUNK;
    if (lo >= N_NODES) return;
    int hi = lo + POOL_CHUNK; if (hi > N_NODES) hi = N_NODES;
    int c = threadIdx.x;
    int g = batch[lo];
    float acc = 0.f;
    for (int n = lo; n < hi; ++n) {
        int gn = batch[n];
        if (gn != g) { atomicAdd(&gsum[g * 256 + c], acc); acc = 0.f; g = gn; }
        acc += x[(size_t)n * 256 + c];
    }
    atomicAdd(&gsum[g * 256 + c], acc);
}

// ---------------- FC head (graph bounds via in-kernel binary search) --------
__global__ __launch_bounds__(256) void fc_head(const float* __restrict__ gsum,
                                               const int* __restrict__ batch,
                                               const float* __restrict__ Wfc,
                                               const float* __restrict__ bfc,
                                               float* __restrict__ out) {
    int g = blockIdx.x;
    int c = threadIdx.x;
    int lo = 0, hi = N_NODES;
    while (lo < hi) { int m = (lo + hi) >> 1; if (batch[m] < g) lo = m + 1; else hi = m; }
    int lo2 = lo, hi2 = N_NODES;
    while (lo2 < hi2) { int m = (lo2 + hi2) >> 1; if (batch[m] < g + 1) lo2 = m + 1; else hi2 = m; }
    float inv = 1.0f / fmaxf((float)(lo2 - lo), 1.0f);
    __shared__ float pooled[256];
    pooled[c] = gsum[(size_t)g * 256 + c] * inv;
    __syncthreads();
    if (c < N_CLASSES) {
        float acc = bfc[c];
        for (int k = 0; k < 256; ++k) acc += pooled[k] * Wfc[k * N_CLASSES + c];
        out[g * N_CLASSES + c] = acc;
    }
}

extern "C" void kernel_launch(void* const* d_in, const int* in_sizes, int n_in,
                              void* d_out, int out_size, void* d_ws, size_t ws_size,
                              hipStream_t stream) {
    const float* emb  = (const float*)d_in[0];
    const int*   eidx = (const int*)d_in[1];
    const int*   batch= (const int*)d_in[2];
    const float* W1   = (const float*)d_in[3];
    const float* b1   = (const float*)d_in[4];
    const float* W2   = (const float*)d_in[5];
    const float* b2   = (const float*)d_in[6];
    const float* Wfc  = (const float*)d_in[7];
    const float* bfc  = (const float*)d_in[8];
    float* out = (float*)d_out;

    const int* src = eidx;
    const int* dst = eidx + N_EDGES;

    char* ws = (char*)d_ws;
    size_t off = 0;
    auto alloc = [&](size_t bytes) { void* p = ws + off; off += (bytes + 1023) & ~(size_t)1023; return p; };
    int*   rowcnt   = (int*)alloc(N_NODES * 4);
    int*   rowstart = (int*)alloc((N_NODES + 1) * 4);
    int*   cursor   = (int*)alloc(N_NODES * 4);
    int*   col      = (int*)alloc(N_EDGES * 4);
    float* dinv     = (float*)alloc(N_NODES * 4);
    float* gsum     = (float*)alloc((size_t)N_GRAPHS * 256 * 4);
    unsigned short* W1T = (unsigned short*)alloc((size_t)HIDDEN * IN_DIM * 2);   // [256][768]
    unsigned short* W2T = (unsigned short*)alloc((size_t)HIDDEN * HIDDEN * 2);   // [256][256]
    unsigned short* bufH = (unsigned short*)alloc((size_t)N_NODES * 256 * 2);    // h (bf16)
    unsigned short* x1 = (unsigned short*)alloc((size_t)N_NODES * 256 * 2);      // bf16
    float* x2 = (float*)alloc((size_t)N_NODES * 256 * 4);                        // f32

    const int NB = (N_NODES + 255) / 256;
    const int EBk = (N_EDGES + 255) / 256;
    const int AGG_B = (N_NODES * 64 + 255) / 256;  // 12500
    dim3 gemm_grid((N_NODES + 63) / 64, 1);        // 782 blocks, full N per block
    const int POOL_B = (N_NODES + POOL_CHUNK - 1) / POOL_CHUNK;  // 1021

    // CSR + norm
    zero_int<<<NB, 256, 0, stream>>>(rowcnt, N_NODES);
    hist_dst<<<EBk, 256, 0, stream>>>(dst, rowcnt);
    scan_kernel<<<1, 1024, 0, stream>>>(rowcnt, rowstart, cursor, dinv);
    scatter_edges<<<EBk, 256, 0, stream>>>(src, dst, cursor, col);
    zero_f32<<<(N_GRAPHS * 256 + 255) / 256, 256, 0, stream>>>(gsum, N_GRAPHS * 256);

    // weight transposes (bf16)
    transpose_w_bf16<<<dim3(IN_DIM / 32, 8), 256, 0, stream>>>(W1, W1T, IN_DIM);
    transpose_w_bf16<<<dim3(HIDDEN / 32, 8), 256, 0, stream>>>(W2, W2T, HIDDEN);

    // conv1: h1 = emb @ W1 (f32 A converted in-staging), then agg -> x1 (bf16, relu)
    gemm_mfma<IN_DIM, true><<<gemm_grid, 256, 0, stream>>>(emb, W1T, bufH, N_NODES);
    agg_csr<true, true><<<AGG_B, 256, 0, stream>>>(bufH, dinv, rowstart, col, b1, x1);

    // conv2: h2 = x1 @ W2, then agg -> x2 (f32)
    gemm_mfma<HIDDEN, false><<<gemm_grid, 256, 0, stream>>>(x1, W2T, bufH, N_NODES);
    agg_csr<false, false><<<AGG_B, 256, 0, stream>>>(bufH, dinv, rowstart, col, b2, x2);

    // pool + head
    pool_partial<<<POOL_B, 256, 0, stream>>>(x2, batch, gsum);
    fc_head<<<N_GRAPHS, 256, 0, stream>>>(gsum, batch, Wfc, bfc, out);
}